// Round 4
// baseline (1304.673 us; speedup 1.0000x reference)
//
#include <hip/hip_runtime.h>
#include <hip/hip_bf16.h>

typedef short short8 __attribute__((ext_vector_type(8)));
typedef float f32x4 __attribute__((ext_vector_type(4)));
typedef unsigned short u16;
typedef unsigned int u32;

__device__ __forceinline__ u16 bf16rne(float f) {
    u32 u = __float_as_uint(f);
    u32 r = (u + 0x7fffu + ((u >> 16) & 1u)) >> 16;
    return (u16)r;
}
__device__ __forceinline__ float bf2f(u16 s) {
    return __uint_as_float(((u32)s) << 16);
}

// LDS-only barrier: wave-sync + LDS visibility WITHOUT draining vmcnt, so
// prefetch loads stay in flight across barriers.
__device__ __forceinline__ void ldsbar() {
    asm volatile("s_waitcnt lgkmcnt(0)" ::: "memory");
    __builtin_amdgcn_s_barrier();
    asm volatile("" ::: "memory");
}

// ---------------------------------------------------------------------------
// Weight swizzle into MFMA B-fragment order, bf16 (unchanged).
// ---------------------------------------------------------------------------
__device__ __forceinline__ void swz(const float* __restrict__ src,
                                    u16* __restrict__ dst, int K, int KT,
                                    int tid0, int stride) {
    int total = 4 * KT * 512;
    for (int i = tid0; i < total; i += stride) {
        int j = i & 7, lane = (i >> 3) & 63, g = i >> 9;
        int kt = g % KT;
        int k = kt * 32 + (lane >> 4) * 8 + j;
        int n = (g / KT) * 16 + (lane & 15);
        dst[i] = (k < K) ? bf16rne(src[k * 64 + n]) : (u16)0;
    }
}

__global__ void prep_weights(
    const float* ev1, const float* ev2, const float* ec1, const float* ec2,
    const float* cg1, const float* cg2, const float* cf1, const float* cf2,
    const float* vg1, const float* vg2, const float* vf1, const float* vf2,
    const float* t1,
    u16* dev1, u16* dev2, u16* dec1, u16* dec2, u16* dcg1, u16* dcg2,
    u16* dcf1, u16* dcf2, u16* dvg1, u16* dvg2, u16* dvf1, u16* dvf2,
    u16* dt1) {
    int tid0 = blockIdx.x * blockDim.x + threadIdx.x;
    int st = gridDim.x * blockDim.x;
    swz(ev1, dev1, 19, 1, tid0, st);
    swz(ev2, dev2, 64, 2, tid0, st);
    swz(ec1, dec1, 5, 1, tid0, st);
    swz(ec2, dec2, 64, 2, tid0, st);
    swz(cg1, dcg1, 129, 5, tid0, st);
    swz(cg2, dcg2, 64, 2, tid0, st);
    swz(cf1, dcf1, 128, 4, tid0, st);
    swz(cf2, dcf2, 64, 2, tid0, st);
    swz(vg1, dvg1, 129, 5, tid0, st);
    swz(vg2, dvg2, 64, 2, tid0, st);
    swz(vf1, dvf1, 128, 4, tid0, st);
    swz(vf2, dvf2, 64, 2, tid0, st);
    swz(t1, dt1, 64, 2, tid0, st);
}

// ---------------------------------------------------------------------------
// Fused counting-sort for BOTH sides. cnt/cursor concatenated
// [c-counts(NC) | v-counts(NV)]; joint exclusive scan -> c positions in
// [0,NE), v positions in [NE,2NE) of packed epk[2NE] = {dst, src, ev, 0}.
// After scatter2, cursor[gd] = END offset of dest gd (CSR, since ranges are
// contiguous: start[gd] = cursor[gd-1]).
// ---------------------------------------------------------------------------
#define SCAN_CHUNK 4096

__global__ void hist2(const int* __restrict__ ci, const int* __restrict__ vi,
                      int ne, int nc, int* __restrict__ cnt) {
    int i = blockIdx.x * blockDim.x + threadIdx.x;
    int st = gridDim.x * blockDim.x;
    for (; i < ne; i += st) {
        atomicAdd(&cnt[ci[i]], 1);
        atomicAdd(&cnt[nc + vi[i]], 1);
    }
}

__global__ void scan_part(const int* __restrict__ cnt, int nd,
                          int* __restrict__ bsum) {
    __shared__ int sred[256];
    int b = blockIdx.x, t = threadIdx.x;
    int base = b * SCAN_CHUNK + t * 16;
    int s = 0;
#pragma unroll
    for (int j = 0; j < 16; j++) {
        int i = base + j;
        if (i < nd) s += cnt[i];
    }
    sred[t] = s;
    __syncthreads();
    for (int o = 128; o > 0; o >>= 1) {
        if (t < o) sred[t] += sred[t + o];
        __syncthreads();
    }
    if (t == 0) bsum[b] = sred[0];
}

__global__ void scan_bsum(int* bsum, int nb) {
    if (threadIdx.x == 0 && blockIdx.x == 0) {
        int run = 0;
        for (int i = 0; i < nb; i++) {
            int v = bsum[i];
            bsum[i] = run;
            run += v;
        }
    }
}

__global__ void scan_final(const int* __restrict__ cnt, int nd,
                           const int* __restrict__ bsum,
                           int* __restrict__ cursor) {
    __shared__ int sa[256];
    int b = blockIdx.x, t = threadIdx.x;
    int base = b * SCAN_CHUNK + t * 16;
    int loc[16];
    int s = 0;
#pragma unroll
    for (int j = 0; j < 16; j++) {
        int i = base + j;
        int v = (i < nd) ? cnt[i] : 0;
        loc[j] = s;
        s += v;
    }
    sa[t] = s;
    __syncthreads();
    int inc = s;
    for (int o = 1; o < 256; o <<= 1) {
        int v = (t >= o) ? sa[t - o] : 0;
        __syncthreads();
        sa[t] += v;
        __syncthreads();
    }
    int off = bsum[b] + sa[t] - inc;
#pragma unroll
    for (int j = 0; j < 16; j++) {
        int i = base + j;
        if (i < nd) cursor[i] = off + loc[j];
    }
}

__global__ void scatter2(const int* __restrict__ ci, const int* __restrict__ vi,
                         const float* __restrict__ ev, int ne, int nc,
                         int* __restrict__ cursor, int4* __restrict__ epk) {
    int i = blockIdx.x * blockDim.x + threadIdx.x;
    int st = gridDim.x * blockDim.x;
    for (; i < ne; i += st) {
        int cd = ci[i], vd = vi[i];
        int eb = __float_as_int(ev[i]);
        int pc = atomicAdd(&cursor[cd], 1);
        int pv = atomicAdd(&cursor[nc + vd], 1);
        epk[pc] = make_int4(cd, vd, eb, 0);
        epk[pv] = make_int4(vd, cd, eb, 0);
    }
}

// ---------------------------------------------------------------------------
// Generic MFMA layer (unchanged).
// ---------------------------------------------------------------------------
template <int KT, int SA>
__device__ __forceinline__ void mfma_layer(const u16* __restrict__ Asrc,
                                           const short8* wf, float bv,
                                           u16* __restrict__ Hdst,
                                           int l15, int lq, int w) {
#pragma unroll
    for (int mt = 0; mt < 4; mt++) {
        f32x4 acc = {0.f, 0.f, 0.f, 0.f};
#pragma unroll
        for (int kt = 0; kt < KT; kt++) {
            short8 a = *(const short8*)(Asrc + (mt * 16 + l15) * SA + kt * 32 + lq * 8);
            acc = __builtin_amdgcn_mfma_f32_16x16x32_bf16(a, wf[kt], acc, 0, 0, 0);
        }
#pragma unroll
        for (int r = 0; r < 4; r++)
            Hdst[(mt * 16 + lq * 4 + r) * 72 + w * 16 + l15] =
                bf16rne(fmaxf(acc[r] + bv, 0.f));
    }
}

// ---------------------------------------------------------------------------
// Input node MLP (unchanged).
// ---------------------------------------------------------------------------
template <int KIN>
__global__ __launch_bounds__(256, 6) void node_mlp_in(
    const float* __restrict__ x, int n_nodes,
    const u16* __restrict__ w1s, const float* __restrict__ b1,
    const u16* __restrict__ w2s, const float* __restrict__ b2,
    u16* __restrict__ outbf) {
    __shared__ __align__(16) u16 A[64 * 40];
    __shared__ __align__(16) u16 H1[64 * 72];
    __shared__ __align__(16) u16 H2[64 * 72];
    int tid = threadIdx.x, l = tid & 63, w = tid >> 6;
    int l15 = l & 15, lq = l >> 4;
    int blk0 = blockIdx.x * 64;
    const int PW = 40 - KIN;
    for (int i = tid; i < 64 * PW; i += 256) {
        int r = i / PW, cc = KIN + (i - r * PW);
        A[r * 40 + cc] = 0;
    }
    for (int i = tid; i < 64 * KIN; i += 256) {
        int r = i / KIN, k = i - r * KIN;
        int gn = blk0 + r; if (gn >= n_nodes) gn = n_nodes - 1;
        A[r * 40 + k] = bf16rne(x[(size_t)gn * KIN + k]);
    }
    short8 w1f[1], w2f[2];
    w1f[0] = *(const short8*)(w1s + ((w * 1 + 0) * 64 + l) * 8);
#pragma unroll
    for (int kt = 0; kt < 2; kt++)
        w2f[kt] = *(const short8*)(w2s + ((w * 2 + kt) * 64 + l) * 8);
    float b1v = b1[w * 16 + l15], b2v = b2[w * 16 + l15];
    ldsbar();
    mfma_layer<1, 40>(A, w1f, b1v, H1, l15, lq, w);
    ldsbar();
    mfma_layer<2, 72>(H1, w2f, b2v, H2, l15, lq, w);
    ldsbar();
    for (int i = tid; i < 512; i += 256) {
        int r = i >> 3, c = i & 7;
        if (blk0 + r < n_nodes)
            *(uint4*)(outbf + (size_t)(blk0 + r) * 64 + c * 8) =
                *(const uint4*)(H2 + r * 72 + c * 8);
    }
}

// ---------------------------------------------------------------------------
// f-MLP staging (unchanged).
// ---------------------------------------------------------------------------
__device__ __forceinline__ void stage_concat_res(
    const u16* __restrict__ ubf, const float* __restrict__ agg,
    int blk0, int n_nodes, u16* __restrict__ A, int tid) {
    for (int i = tid; i < 64 * 24; i += 256) {
        int nd = i / 24, c = i - nd * 24;
        int gn = blk0 + nd; if (gn >= n_nodes) gn = n_nodes - 1;
        if (c < 8) {
            *(uint4*)(A + nd * 200 + c * 8) =
                *(const uint4*)(ubf + (size_t)gn * 64 + c * 8);
        } else {
            int q = c - 8;
            float4 av = *(const float4*)(agg + (size_t)gn * 64 + q * 4);
            u16 h0 = bf16rne(av.x), h1 = bf16rne(av.y);
            u16 h2 = bf16rne(av.z), h3 = bf16rne(av.w);
            uint2 hi;
            hi.x = (u32)h0 | ((u32)h1 << 16);
            hi.y = (u32)h2 | ((u32)h3 << 16);
            *(uint2*)(A + nd * 200 + 64 + q * 4) = hi;
            uint2 rs;
            rs.x = (u32)bf16rne(av.x - bf2f(h0)) | ((u32)bf16rne(av.y - bf2f(h1)) << 16);
            rs.y = (u32)bf16rne(av.z - bf2f(h2)) | ((u32)bf16rne(av.w - bf2f(h3)) << 16);
            *(uint2*)(A + nd * 200 + 128 + q * 4) = rs;
        }
    }
}

// ---------------------------------------------------------------------------
// c-side f-MLP (unchanged).
// ---------------------------------------------------------------------------
__global__ __launch_bounds__(256, 4) void node_mlp_f(
    const u16* __restrict__ ubf, const float* __restrict__ agg, int n_nodes,
    const u16* __restrict__ w1s, const float* __restrict__ b1,
    const u16* __restrict__ w2s, const float* __restrict__ b2,
    u16* __restrict__ outbf) {
    __shared__ __align__(16) u16 A[64 * 200];
    __shared__ __align__(16) u16 H1[64 * 72];
    int tid = threadIdx.x, l = tid & 63, w = tid >> 6;
    int l15 = l & 15, lq = l >> 4;
    int blk0 = blockIdx.x * 64;
    stage_concat_res(ubf, agg, blk0, n_nodes, A, tid);
    short8 w1f[6], w2f[2];
#pragma unroll
    for (int kt = 0; kt < 4; kt++)
        w1f[kt] = *(const short8*)(w1s + ((w * 4 + kt) * 64 + l) * 8);
    w1f[4] = w1f[2];
    w1f[5] = w1f[3];
#pragma unroll
    for (int kt = 0; kt < 2; kt++)
        w2f[kt] = *(const short8*)(w2s + ((w * 2 + kt) * 64 + l) * 8);
    float b1v = b1[w * 16 + l15], b2v = b2[w * 16 + l15];
    ldsbar();
    mfma_layer<6, 200>(A, w1f, b1v, H1, l15, lq, w);
    ldsbar();
    mfma_layer<2, 72>(H1, w2f, b2v, A, l15, lq, w);
    ldsbar();
    for (int i = tid; i < 512; i += 256) {
        int r = i >> 3, c = i & 7;
        if (blk0 + r < n_nodes)
            *(uint4*)(outbf + (size_t)(blk0 + r) * 64 + c * 8) =
                *(const uint4*)(A + r * 72 + c * 8);
    }
}

// ---------------------------------------------------------------------------
// v-side f-MLP + tail (unchanged).
// ---------------------------------------------------------------------------
__global__ __launch_bounds__(256, 3) void node_mlp_vf_tail(
    const u16* __restrict__ vbf, const float* __restrict__ agg, int n_nodes,
    const u16* __restrict__ w1s, const float* __restrict__ b1,
    const u16* __restrict__ w2s, const float* __restrict__ b2,
    const u16* __restrict__ t1s, const float* __restrict__ tb1,
    const float* __restrict__ tw2, const float* __restrict__ tb2,
    float* __restrict__ out) {
    __shared__ __align__(16) char smem[64 * 200 * 2 + 2 * 64 * 72 * 2];
    u16* A = (u16*)smem;
    float* XF = (float*)smem;
    u16* H1 = (u16*)(smem + 25600);
    u16* H2 = (u16*)(smem + 25600 + 9216);
    int tid = threadIdx.x, l = tid & 63, w = tid >> 6;
    int l15 = l & 15, lq = l >> 4;
    int blk0 = blockIdx.x * 64;
    stage_concat_res(vbf, agg, blk0, n_nodes, A, tid);
    short8 w1f[6], w2f[2], t1f[2];
#pragma unroll
    for (int kt = 0; kt < 4; kt++)
        w1f[kt] = *(const short8*)(w1s + ((w * 4 + kt) * 64 + l) * 8);
    w1f[4] = w1f[2];
    w1f[5] = w1f[3];
#pragma unroll
    for (int kt = 0; kt < 2; kt++) {
        w2f[kt] = *(const short8*)(w2s + ((w * 2 + kt) * 64 + l) * 8);
        t1f[kt] = *(const short8*)(t1s + ((w * 2 + kt) * 64 + l) * 8);
    }
    float b1v = b1[w * 16 + l15], b2v = b2[w * 16 + l15];
    float tb1v = tb1[w * 16 + l15];
    ldsbar();
    mfma_layer<6, 200>(A, w1f, b1v, H1, l15, lq, w);
    ldsbar();
    mfma_layer<2, 72>(H1, w2f, b2v, H2, l15, lq, w);
    ldsbar();
#pragma unroll
    for (int mt = 0; mt < 4; mt++) {
        f32x4 acc = {0.f, 0.f, 0.f, 0.f};
#pragma unroll
        for (int kt = 0; kt < 2; kt++) {
            short8 a = *(const short8*)(H2 + (mt * 16 + l15) * 72 + kt * 32 + lq * 8);
            acc = __builtin_amdgcn_mfma_f32_16x16x32_bf16(a, t1f[kt], acc, 0, 0, 0);
        }
#pragma unroll
        for (int r = 0; r < 4; r++)
            XF[(mt * 16 + lq * 4 + r) * 65 + w * 16 + l15] =
                fmaxf(acc[r] + tb1v, 0.f);
    }
    ldsbar();
    float s0 = tb2[2 * w], s1 = tb2[2 * w + 1];
    for (int k = 0; k < 64; k++) {
        float xk = XF[l * 65 + k];
        float2 wp = *(const float2*)(tw2 + k * 8 + 2 * w);
        s0 = fmaf(xk, wp.x, s0);
        s1 = fmaf(xk, wp.y, s1);
    }
    if (blk0 + l < n_nodes) {
        float2 r;
        r.x = 1.f / (1.f + __expf(-s0));
        r.y = 1.f / (1.f + __expf(-s1));
        *(float2*)(out + (size_t)(blk0 + l) * 8 + 2 * w) = r;
    }
}

// ---------------------------------------------------------------------------
// Edge conv, R8: CSR dest-range blocks + LDS accumulator.
// Each block owns destinations [d0s, d0s+DPB) exclusively and processes its
// exact CSR edge range in 64-edge tiles. L2-MFMA outputs are ds_add'ed
// straight from registers into the per-block LDS accumulator (no G tile, no
// run-scan, no global atomics). 2 barriers/tile. Block end: one coalesced
// plain-store flush (covers zero-degree dests -> no agg memset needed).
// LDS = 21504(A) + 9216(Hs) + 256(Didx) + 8192(acc) = 39168 B -> 4 blocks/CU.
// ---------------------------------------------------------------------------
#define AROW 168
#define HROW 72
#define DPB 32

__global__ __launch_bounds__(256, 4) void edge_conv(
    const u16* __restrict__ u_feat, const u16* __restrict__ v_feat,
    const int4* __restrict__ epk,      // full packed edge array (both sides)
    const int* __restrict__ cursor,    // CSR end-offsets, concatenated dests
    int gd_base, int ndst,             // global dest base, #dests this side
    const u16* __restrict__ w1s, const u16* __restrict__ w2s,
    const float* __restrict__ b1, const float* __restrict__ b2,
    float* __restrict__ agg) {
    __shared__ __align__(16) u16 A[64 * AROW];
    __shared__ __align__(16) u16 Hs[64 * HROW];
    __shared__ int Didx[64];           // local dest per row, -1 = pad
    __shared__ __align__(16) float accs[DPB * 64];

    int tid = threadIdx.x;
    int lane = tid & 63;
    int w = tid >> 6;
    int l15 = lane & 15, lq = lane >> 4;
    int cch = tid & 15, e0row = tid >> 4;

    int d0s = (int)blockIdx.x * DPB;       // side-local dest base
    if (d0s >= ndst) return;
    int nloc = ndst - d0s; if (nloc > DPB) nloc = DPB;
    int gd0 = gd_base + d0s;
    int e0 = (gd0 == 0) ? 0 : cursor[gd0 - 1];
    int e1 = cursor[gd0 + nloc - 1];

    // zero acc + zero pad cols [129,168)
    for (int i = tid; i < DPB * 64; i += 256) accs[i] = 0.f;
    for (int i = tid; i < 64 * (AROW - 129); i += 256) {
        int r = i / (AROW - 129);
        int cc = 129 + (i - r * (AROW - 129));
        A[r * AROW + cc] = 0;
    }

    short8 w1f[5], w2f[2];
#pragma unroll
    for (int kt = 0; kt < 5; kt++)
        w1f[kt] = *(const short8*)(w1s + ((w * 5 + kt) * 64 + lane) * 8);
#pragma unroll
    for (int kt = 0; kt < 2; kt++)
        w2f[kt] = *(const short8*)(w2s + ((w * 2 + kt) * 64 + lane) * 8);
    float b1v = b1[w * 16 + l15];
    float b2v = b2[w * 16 + l15];

    const bool fsel = (cch < 8);
    const u16* fbase = fsel ? u_feat : v_feat;
    const int gcol = fsel ? cch * 8 : 64 + (cch - 8) * 8;
    const int coff = (cch & 7) * 8;
    const int* epki = (const int*)epk;

    int ntl = (e1 - e0 + 63) >> 6;         // tiles in this block's range

    uint4 st[4];   // staged features, current tile
    u32 evb[4];    // e_val bits, current tile
    int4 pe[4];    // packed edges, NEXT tile
    int ddx = -1, ddx_n = -1;

    if (ntl > 0) {
        // prologue: stage tile 0 directly, prefetch epk of tile 1
#pragma unroll
        for (int t = 0; t < 4; t++) {
            int le = e0 + e0row + t * 16; if (le >= e1) le = e1 - 1;
            int4 e = epk[le];
            int ix = fsel ? e.x : e.y;
            st[t] = *(const uint4*)(fbase + (size_t)ix * 64 + coff);
            evb[t] = (u32)e.z;
        }
        if (tid < 64) {
            int le = e0 + tid;
            ddx = (le < e1) ? (epki[le * 4] - d0s) : -1;
        }
        if (ntl > 1) {
            int b2b = e0 + 64;
#pragma unroll
            for (int t = 0; t < 4; t++) {
                int le = b2b + e0row + t * 16; if (le >= e1) le = e1 - 1;
                pe[t] = epk[le];
            }
            if (tid < 64) {
                int le = b2b + tid;
                ddx_n = (le < e1) ? (epki[le * 4] - d0s) : -1;
            }
        }
    }

    for (int tl = 0; tl < ntl; ++tl) {
        // commit staged regs to LDS (cols 0..128) + local dest ids
#pragma unroll
        for (int t = 0; t < 4; t++) {
            int e = e0row + t * 16;
            *(uint4*)(&A[e * AROW + gcol]) = st[t];
            if (cch == 0) A[e * AROW + 128] = bf16rne(__uint_as_float(evb[t]));
        }
        if (tid < 64) Didx[tid] = ddx;
        // pipeline: gather tile+1 features (epk in regs), prefetch epk tile+2
        if (tl + 1 < ntl) {
#pragma unroll
            for (int t = 0; t < 4; t++) {
                int ix = fsel ? pe[t].x : pe[t].y;
                st[t] = *(const uint4*)(fbase + (size_t)ix * 64 + coff);
                evb[t] = (u32)pe[t].z;
            }
            ddx = ddx_n;
            if (tl + 2 < ntl) {
                int b2b = e0 + (tl + 2) * 64;
#pragma unroll
                for (int t = 0; t < 4; t++) {
                    int le = b2b + e0row + t * 16; if (le >= e1) le = e1 - 1;
                    pe[t] = epk[le];
                }
                if (tid < 64) {
                    int le = b2b + tid;
                    ddx_n = (le < e1) ? (epki[le * 4] - d0s) : -1;
                }
            }
        }
        ldsbar();  // B1: A + Didx staged (also: prev L1's A reads done)

#pragma unroll
        for (int mt = 0; mt < 4; mt++) {
            short8 a1[5];
#pragma unroll
            for (int kt = 0; kt < 5; kt++)
                a1[kt] = *(const short8*)(&A[(mt * 16 + l15) * AROW + kt * 32 + lq * 8]);
            f32x4 acc = {0.f, 0.f, 0.f, 0.f};
#pragma unroll
            for (int kt = 0; kt < 5; kt++)
                acc = __builtin_amdgcn_mfma_f32_16x16x32_bf16(a1[kt], w1f[kt], acc, 0, 0, 0);
#pragma unroll
            for (int r = 0; r < 4; r++) {
                float hv = fmaxf(acc[r] + b1v, 0.f);
                Hs[(mt * 16 + lq * 4 + r) * HROW + w * 16 + l15] = bf16rne(hv);
            }
        }
        ldsbar();  // B2: Hs ready (also: prev L2's Hs reads done)

        // L2 MFMA + direct ds_add into acc from registers
#pragma unroll
        for (int mt = 0; mt < 4; mt++) {
            short8 a2[2];
#pragma unroll
            for (int kt = 0; kt < 2; kt++)
                a2[kt] = *(const short8*)(&Hs[(mt * 16 + l15) * HROW + kt * 32 + lq * 8]);
            f32x4 acc = {0.f, 0.f, 0.f, 0.f};
#pragma unroll
            for (int kt = 0; kt < 2; kt++)
                acc = __builtin_amdgcn_mfma_f32_16x16x32_bf16(a2[kt], w2f[kt], acc, 0, 0, 0);
#pragma unroll
            for (int r = 0; r < 4; r++) {
                int row = mt * 16 + lq * 4 + r;
                int ld = Didx[row];
                float gv = fmaxf(acc[r] + b2v, 0.f);
                if (ld >= 0)
                    atomicAdd(&accs[ld * 64 + w * 16 + l15], gv);
            }
        }
    }

    ldsbar();  // all ds_adds visible
    // coalesced flush: every dest in [d0s, d0s+nloc) written exactly once
    for (int i = tid * 4; i < nloc * 64; i += 1024)
        *(float4*)(agg + (size_t)d0s * 64 + i) = *(const float4*)(accs + i);
}

extern "C" void kernel_launch(void* const* d_in, const int* in_sizes, int n_in,
                              void* d_out, int out_size, void* d_ws, size_t ws_size,
                              hipStream_t stream) {
    const float* v        = (const float*)d_in[0];
    const float* c        = (const float*)d_in[1];
    const int*   cons_idx = (const int*)d_in[2];
    const int*   var_idx  = (const int*)d_in[3];
    const float* e_val    = (const float*)d_in[4];
    const float* ev_w1 = (const float*)d_in[5],  *ev_b1 = (const float*)d_in[6];
    const float* ev_w2 = (const float*)d_in[7],  *ev_b2 = (const float*)d_in[8];
    const float* ec_w1 = (const float*)d_in[9],  *ec_b1 = (const float*)d_in[10];
    const float* ec_w2 = (const float*)d_in[11], *ec_b2 = (const float*)d_in[12];
    const float* cg_w1 = (const float*)d_in[13], *cg_b1 = (const float*)d_in[14];
    const float* cg_w2 = (const float*)d_in[15], *cg_b2 = (const float*)d_in[16];
    const float* cf_w1 = (const float*)d_in[17], *cf_b1 = (const float*)d_in[18];
    const float* cf_w2 = (const float*)d_in[19], *cf_b2 = (const float*)d_in[20];
    const float* vg_w1 = (const float*)d_in[21], *vg_b1 = (const float*)d_in[22];
    const float* vg_w2 = (const float*)d_in[23], *vg_b2 = (const float*)d_in[24];
    const float* vf_w1 = (const float*)d_in[25], *vf_b1 = (const float*)d_in[26];
    const float* vf_w2 = (const float*)d_in[27], *vf_b2 = (const float*)d_in[28];
    const float* t_w1  = (const float*)d_in[29], *t_b1  = (const float*)d_in[30];
    const float* t_w2  = (const float*)d_in[31], *t_b2  = (const float*)d_in[32];

    const int NV = in_sizes[0] / 19;
    const int NC = in_sizes[1] / 5;
    const int NE = in_sizes[4];

    char* ws = (char*)d_ws;
    size_t off = 0;
    u16* v1bf = (u16*)(ws + off); off += (size_t)NV * 64 * 2;
    u16* c1bf = (u16*)(ws + off); off += (size_t)NC * 64 * 2;
    u16* c2bf = (u16*)(ws + off); off += (size_t)NC * 64 * 2;
    float* agg_c = (float*)(ws + off); off += (size_t)NC * 64 * 4;
    float* agg_v = (float*)(ws + off); off += (size_t)NV * 64 * 4;
    u16* ev1s = (u16*)(ws + off); off += 2048 * 2;
    u16* ev2s = (u16*)(ws + off); off += 4096 * 2;
    u16* ec1s = (u16*)(ws + off); off += 2048 * 2;
    u16* ec2s = (u16*)(ws + off); off += 4096 * 2;
    u16* cg1s = (u16*)(ws + off); off += 10240 * 2;
    u16* cg2s = (u16*)(ws + off); off += 4096 * 2;
    u16* cf1s = (u16*)(ws + off); off += 8192 * 2;
    u16* cf2s = (u16*)(ws + off); off += 4096 * 2;
    u16* vg1s = (u16*)(ws + off); off += 10240 * 2;
    u16* vg2s = (u16*)(ws + off); off += 4096 * 2;
    u16* vf1s = (u16*)(ws + off); off += 8192 * 2;
    u16* vf2s = (u16*)(ws + off); off += 4096 * 2;
    u16* t1s  = (u16*)(ws + off); off += 4096 * 2;
    off = (off + 255) & ~(size_t)255;
    int* cnt    = (int*)(ws + off); off += (size_t)(NC + NV) * 4;
    int* cursor = (int*)(ws + off); off += (size_t)(NC + NV) * 4;
    int* bsum   = (int*)(ws + off); off += 64 * 4;
    off = (off + 255) & ~(size_t)255;
    int4* epk   = (int4*)(ws + off); off += (size_t)NE * 2 * 16;

    const int nd = NC + NV;
    const int nb = (nd + SCAN_CHUNK - 1) / SCAN_CHUNK;

    prep_weights<<<40, 256, 0, stream>>>(
        ev_w1, ev_w2, ec_w1, ec_w2, cg_w1, cg_w2, cf_w1, cf_w2,
        vg_w1, vg_w2, vf_w1, vf_w2, t_w1,
        ev1s, ev2s, ec1s, ec2s, cg1s, cg2s, cf1s, cf2s,
        vg1s, vg2s, vf1s, vf2s, t1s);

    // fused dual counting sort (c positions in [0,NE), v in [NE,2NE))
    hipMemsetAsync(cnt, 0, (size_t)nd * 4, stream);
    hist2<<<512, 256, 0, stream>>>(cons_idx, var_idx, NE, NC, cnt);
    scan_part<<<nb, 256, 0, stream>>>(cnt, nd, bsum);
    scan_bsum<<<1, 64, 0, stream>>>(bsum, nb);
    scan_final<<<nb, 256, 0, stream>>>(cnt, nd, bsum, cursor);
    scatter2<<<1024, 256, 0, stream>>>(cons_idx, var_idx, e_val, NE, NC,
                                       cursor, epk);

    node_mlp_in<19><<<(NV + 63) / 64, 256, 0, stream>>>(
        v, NV, ev1s, ev_b1, ev2s, ev_b2, v1bf);
    node_mlp_in<5><<<(NC + 63) / 64, 256, 0, stream>>>(
        c, NC, ec1s, ec_b1, ec2s, ec_b2, c1bf);

    // c-side conv + f-MLP (no agg memset: flush covers all dests)
    edge_conv<<<(NC + DPB - 1) / DPB, 256, 0, stream>>>(
        c1bf, v1bf, epk, cursor, 0, NC,
        cg1s, cg2s, cg_b1, cg_b2, agg_c);
    node_mlp_f<<<(NC + 63) / 64, 256, 0, stream>>>(
        c1bf, agg_c, NC, cf1s, cf_b1, cf2s, cf_b2, c2bf);

    // v-side conv + f-MLP + tail
    edge_conv<<<(NV + DPB - 1) / DPB, 256, 0, stream>>>(
        v1bf, c2bf, epk, cursor, NC, NV,
        vg1s, vg2s, vg_b1, vg_b2, agg_v);
    node_mlp_vf_tail<<<(NV + 63) / 64, 256, 0, stream>>>(
        v1bf, agg_v, NV, vf1s, vf_b1, vf2s, vf_b2,
        t1s, t_b1, t_w2, t_b2, (float*)d_out);
}

// Round 5
// 825.340 us; speedup vs baseline: 1.5808x; 1.5808x over previous
//
#include <hip/hip_runtime.h>
#include <hip/hip_bf16.h>

typedef short short8 __attribute__((ext_vector_type(8)));
typedef float f32x4 __attribute__((ext_vector_type(4)));
typedef unsigned short u16;
typedef unsigned int u32;

__device__ __forceinline__ u16 bf16rne(float f) {
    u32 u = __float_as_uint(f);
    u32 r = (u + 0x7fffu + ((u >> 16) & 1u)) >> 16;
    return (u16)r;
}
__device__ __forceinline__ float bf2f(u16 s) {
    return __uint_as_float(((u32)s) << 16);
}

// LDS-only barrier: wave-sync + LDS visibility WITHOUT draining vmcnt, so
// prefetch loads stay in flight across barriers.
__device__ __forceinline__ void ldsbar() {
    asm volatile("s_waitcnt lgkmcnt(0)" ::: "memory");
    __builtin_amdgcn_s_barrier();
    asm volatile("" ::: "memory");
}

// Native LDS float atomic add (ds_add_f32), avoiding the CAS-loop lowering
// that plain atomicAdd(float*) can produce for shared memory.
__device__ __forceinline__ void ds_addf(float* p, float v) {
    __hip_atomic_fetch_add(p, v, __ATOMIC_RELAXED, __HIP_MEMORY_SCOPE_WORKGROUP);
}

// ---------------------------------------------------------------------------
// Weight swizzle into MFMA B-fragment order, bf16 (unchanged).
// ---------------------------------------------------------------------------
__device__ __forceinline__ void swz(const float* __restrict__ src,
                                    u16* __restrict__ dst, int K, int KT,
                                    int tid0, int stride) {
    int total = 4 * KT * 512;
    for (int i = tid0; i < total; i += stride) {
        int j = i & 7, lane = (i >> 3) & 63, g = i >> 9;
        int kt = g % KT;
        int k = kt * 32 + (lane >> 4) * 8 + j;
        int n = (g / KT) * 16 + (lane & 15);
        dst[i] = (k < K) ? bf16rne(src[k * 64 + n]) : (u16)0;
    }
}

__global__ void prep_weights(
    const float* ev1, const float* ev2, const float* ec1, const float* ec2,
    const float* cg1, const float* cg2, const float* cf1, const float* cf2,
    const float* vg1, const float* vg2, const float* vf1, const float* vf2,
    const float* t1,
    u16* dev1, u16* dev2, u16* dec1, u16* dec2, u16* dcg1, u16* dcg2,
    u16* dcf1, u16* dcf2, u16* dvg1, u16* dvg2, u16* dvf1, u16* dvf2,
    u16* dt1) {
    int tid0 = blockIdx.x * blockDim.x + threadIdx.x;
    int st = gridDim.x * blockDim.x;
    swz(ev1, dev1, 19, 1, tid0, st);
    swz(ev2, dev2, 64, 2, tid0, st);
    swz(ec1, dec1, 5, 1, tid0, st);
    swz(ec2, dec2, 64, 2, tid0, st);
    swz(cg1, dcg1, 129, 5, tid0, st);
    swz(cg2, dcg2, 64, 2, tid0, st);
    swz(cf1, dcf1, 128, 4, tid0, st);
    swz(cf2, dcf2, 64, 2, tid0, st);
    swz(vg1, dvg1, 129, 5, tid0, st);
    swz(vg2, dvg2, 64, 2, tid0, st);
    swz(vf1, dvf1, 128, 4, tid0, st);
    swz(vf2, dvf2, 64, 2, tid0, st);
    swz(t1, dt1, 64, 2, tid0, st);
}

// ---------------------------------------------------------------------------
// Fused counting-sort for BOTH sides (unchanged). cursor[gd] ends up as the
// CSR end-offset of dest gd.
// ---------------------------------------------------------------------------
#define SCAN_CHUNK 4096

__global__ void hist2(const int* __restrict__ ci, const int* __restrict__ vi,
                      int ne, int nc, int* __restrict__ cnt) {
    int i = blockIdx.x * blockDim.x + threadIdx.x;
    int st = gridDim.x * blockDim.x;
    for (; i < ne; i += st) {
        atomicAdd(&cnt[ci[i]], 1);
        atomicAdd(&cnt[nc + vi[i]], 1);
    }
}

__global__ void scan_part(const int* __restrict__ cnt, int nd,
                          int* __restrict__ bsum) {
    __shared__ int sred[256];
    int b = blockIdx.x, t = threadIdx.x;
    int base = b * SCAN_CHUNK + t * 16;
    int s = 0;
#pragma unroll
    for (int j = 0; j < 16; j++) {
        int i = base + j;
        if (i < nd) s += cnt[i];
    }
    sred[t] = s;
    __syncthreads();
    for (int o = 128; o > 0; o >>= 1) {
        if (t < o) sred[t] += sred[t + o];
        __syncthreads();
    }
    if (t == 0) bsum[b] = sred[0];
}

__global__ void scan_bsum(int* bsum, int nb) {
    if (threadIdx.x == 0 && blockIdx.x == 0) {
        int run = 0;
        for (int i = 0; i < nb; i++) {
            int v = bsum[i];
            bsum[i] = run;
            run += v;
        }
    }
}

__global__ void scan_final(const int* __restrict__ cnt, int nd,
                           const int* __restrict__ bsum,
                           int* __restrict__ cursor) {
    __shared__ int sa[256];
    int b = blockIdx.x, t = threadIdx.x;
    int base = b * SCAN_CHUNK + t * 16;
    int loc[16];
    int s = 0;
#pragma unroll
    for (int j = 0; j < 16; j++) {
        int i = base + j;
        int v = (i < nd) ? cnt[i] : 0;
        loc[j] = s;
        s += v;
    }
    sa[t] = s;
    __syncthreads();
    int inc = s;
    for (int o = 1; o < 256; o <<= 1) {
        int v = (t >= o) ? sa[t - o] : 0;
        __syncthreads();
        sa[t] += v;
        __syncthreads();
    }
    int off = bsum[b] + sa[t] - inc;
#pragma unroll
    for (int j = 0; j < 16; j++) {
        int i = base + j;
        if (i < nd) cursor[i] = off + loc[j];
    }
}

__global__ void scatter2(const int* __restrict__ ci, const int* __restrict__ vi,
                         const float* __restrict__ ev, int ne, int nc,
                         int* __restrict__ cursor, int4* __restrict__ epk) {
    int i = blockIdx.x * blockDim.x + threadIdx.x;
    int st = gridDim.x * blockDim.x;
    for (; i < ne; i += st) {
        int cd = ci[i], vd = vi[i];
        int eb = __float_as_int(ev[i]);
        int pc = atomicAdd(&cursor[cd], 1);
        int pv = atomicAdd(&cursor[nc + vd], 1);
        epk[pc] = make_int4(cd, vd, eb, 0);
        epk[pv] = make_int4(vd, cd, eb, 0);
    }
}

// ---------------------------------------------------------------------------
// Generic MFMA layer (unchanged).
// ---------------------------------------------------------------------------
template <int KT, int SA>
__device__ __forceinline__ void mfma_layer(const u16* __restrict__ Asrc,
                                           const short8* wf, float bv,
                                           u16* __restrict__ Hdst,
                                           int l15, int lq, int w) {
#pragma unroll
    for (int mt = 0; mt < 4; mt++) {
        f32x4 acc = {0.f, 0.f, 0.f, 0.f};
#pragma unroll
        for (int kt = 0; kt < KT; kt++) {
            short8 a = *(const short8*)(Asrc + (mt * 16 + l15) * SA + kt * 32 + lq * 8);
            acc = __builtin_amdgcn_mfma_f32_16x16x32_bf16(a, wf[kt], acc, 0, 0, 0);
        }
#pragma unroll
        for (int r = 0; r < 4; r++)
            Hdst[(mt * 16 + lq * 4 + r) * 72 + w * 16 + l15] =
                bf16rne(fmaxf(acc[r] + bv, 0.f));
    }
}

// ---------------------------------------------------------------------------
// Input node MLP (unchanged).
// ---------------------------------------------------------------------------
template <int KIN>
__global__ __launch_bounds__(256, 6) void node_mlp_in(
    const float* __restrict__ x, int n_nodes,
    const u16* __restrict__ w1s, const float* __restrict__ b1,
    const u16* __restrict__ w2s, const float* __restrict__ b2,
    u16* __restrict__ outbf) {
    __shared__ __align__(16) u16 A[64 * 40];
    __shared__ __align__(16) u16 H1[64 * 72];
    __shared__ __align__(16) u16 H2[64 * 72];
    int tid = threadIdx.x, l = tid & 63, w = tid >> 6;
    int l15 = l & 15, lq = l >> 4;
    int blk0 = blockIdx.x * 64;
    const int PW = 40 - KIN;
    for (int i = tid; i < 64 * PW; i += 256) {
        int r = i / PW, cc = KIN + (i - r * PW);
        A[r * 40 + cc] = 0;
    }
    for (int i = tid; i < 64 * KIN; i += 256) {
        int r = i / KIN, k = i - r * KIN;
        int gn = blk0 + r; if (gn >= n_nodes) gn = n_nodes - 1;
        A[r * 40 + k] = bf16rne(x[(size_t)gn * KIN + k]);
    }
    short8 w1f[1], w2f[2];
    w1f[0] = *(const short8*)(w1s + ((w * 1 + 0) * 64 + l) * 8);
#pragma unroll
    for (int kt = 0; kt < 2; kt++)
        w2f[kt] = *(const short8*)(w2s + ((w * 2 + kt) * 64 + l) * 8);
    float b1v = b1[w * 16 + l15], b2v = b2[w * 16 + l15];
    ldsbar();
    mfma_layer<1, 40>(A, w1f, b1v, H1, l15, lq, w);
    ldsbar();
    mfma_layer<2, 72>(H1, w2f, b2v, H2, l15, lq, w);
    ldsbar();
    for (int i = tid; i < 512; i += 256) {
        int r = i >> 3, c = i & 7;
        if (blk0 + r < n_nodes)
            *(uint4*)(outbf + (size_t)(blk0 + r) * 64 + c * 8) =
                *(const uint4*)(H2 + r * 72 + c * 8);
    }
}

// ---------------------------------------------------------------------------
// f-MLP staging (unchanged).
// ---------------------------------------------------------------------------
__device__ __forceinline__ void stage_concat_res(
    const u16* __restrict__ ubf, const float* __restrict__ agg,
    int blk0, int n_nodes, u16* __restrict__ A, int tid) {
    for (int i = tid; i < 64 * 24; i += 256) {
        int nd = i / 24, c = i - nd * 24;
        int gn = blk0 + nd; if (gn >= n_nodes) gn = n_nodes - 1;
        if (c < 8) {
            *(uint4*)(A + nd * 200 + c * 8) =
                *(const uint4*)(ubf + (size_t)gn * 64 + c * 8);
        } else {
            int q = c - 8;
            float4 av = *(const float4*)(agg + (size_t)gn * 64 + q * 4);
            u16 h0 = bf16rne(av.x), h1 = bf16rne(av.y);
            u16 h2 = bf16rne(av.z), h3 = bf16rne(av.w);
            uint2 hi;
            hi.x = (u32)h0 | ((u32)h1 << 16);
            hi.y = (u32)h2 | ((u32)h3 << 16);
            *(uint2*)(A + nd * 200 + 64 + q * 4) = hi;
            uint2 rs;
            rs.x = (u32)bf16rne(av.x - bf2f(h0)) | ((u32)bf16rne(av.y - bf2f(h1)) << 16);
            rs.y = (u32)bf16rne(av.z - bf2f(h2)) | ((u32)bf16rne(av.w - bf2f(h3)) << 16);
            *(uint2*)(A + nd * 200 + 128 + q * 4) = rs;
        }
    }
}

// ---------------------------------------------------------------------------
// c-side f-MLP (unchanged).
// ---------------------------------------------------------------------------
__global__ __launch_bounds__(256, 4) void node_mlp_f(
    const u16* __restrict__ ubf, const float* __restrict__ agg, int n_nodes,
    const u16* __restrict__ w1s, const float* __restrict__ b1,
    const u16* __restrict__ w2s, const float* __restrict__ b2,
    u16* __restrict__ outbf) {
    __shared__ __align__(16) u16 A[64 * 200];
    __shared__ __align__(16) u16 H1[64 * 72];
    int tid = threadIdx.x, l = tid & 63, w = tid >> 6;
    int l15 = l & 15, lq = l >> 4;
    int blk0 = blockIdx.x * 64;
    stage_concat_res(ubf, agg, blk0, n_nodes, A, tid);
    short8 w1f[6], w2f[2];
#pragma unroll
    for (int kt = 0; kt < 4; kt++)
        w1f[kt] = *(const short8*)(w1s + ((w * 4 + kt) * 64 + l) * 8);
    w1f[4] = w1f[2];
    w1f[5] = w1f[3];
#pragma unroll
    for (int kt = 0; kt < 2; kt++)
        w2f[kt] = *(const short8*)(w2s + ((w * 2 + kt) * 64 + l) * 8);
    float b1v = b1[w * 16 + l15], b2v = b2[w * 16 + l15];
    ldsbar();
    mfma_layer<6, 200>(A, w1f, b1v, H1, l15, lq, w);
    ldsbar();
    mfma_layer<2, 72>(H1, w2f, b2v, A, l15, lq, w);
    ldsbar();
    for (int i = tid; i < 512; i += 256) {
        int r = i >> 3, c = i & 7;
        if (blk0 + r < n_nodes)
            *(uint4*)(outbf + (size_t)(blk0 + r) * 64 + c * 8) =
                *(const uint4*)(A + r * 72 + c * 8);
    }
}

// ---------------------------------------------------------------------------
// v-side f-MLP + tail (unchanged).
// ---------------------------------------------------------------------------
__global__ __launch_bounds__(256, 3) void node_mlp_vf_tail(
    const u16* __restrict__ vbf, const float* __restrict__ agg, int n_nodes,
    const u16* __restrict__ w1s, const float* __restrict__ b1,
    const u16* __restrict__ w2s, const float* __restrict__ b2,
    const u16* __restrict__ t1s, const float* __restrict__ tb1,
    const float* __restrict__ tw2, const float* __restrict__ tb2,
    float* __restrict__ out) {
    __shared__ __align__(16) char smem[64 * 200 * 2 + 2 * 64 * 72 * 2];
    u16* A = (u16*)smem;
    float* XF = (float*)smem;
    u16* H1 = (u16*)(smem + 25600);
    u16* H2 = (u16*)(smem + 25600 + 9216);
    int tid = threadIdx.x, l = tid & 63, w = tid >> 6;
    int l15 = l & 15, lq = l >> 4;
    int blk0 = blockIdx.x * 64;
    stage_concat_res(vbf, agg, blk0, n_nodes, A, tid);
    short8 w1f[6], w2f[2], t1f[2];
#pragma unroll
    for (int kt = 0; kt < 4; kt++)
        w1f[kt] = *(const short8*)(w1s + ((w * 4 + kt) * 64 + l) * 8);
    w1f[4] = w1f[2];
    w1f[5] = w1f[3];
#pragma unroll
    for (int kt = 0; kt < 2; kt++) {
        w2f[kt] = *(const short8*)(w2s + ((w * 2 + kt) * 64 + l) * 8);
        t1f[kt] = *(const short8*)(t1s + ((w * 2 + kt) * 64 + l) * 8);
    }
    float b1v = b1[w * 16 + l15], b2v = b2[w * 16 + l15];
    float tb1v = tb1[w * 16 + l15];
    ldsbar();
    mfma_layer<6, 200>(A, w1f, b1v, H1, l15, lq, w);
    ldsbar();
    mfma_layer<2, 72>(H1, w2f, b2v, H2, l15, lq, w);
    ldsbar();
#pragma unroll
    for (int mt = 0; mt < 4; mt++) {
        f32x4 acc = {0.f, 0.f, 0.f, 0.f};
#pragma unroll
        for (int kt = 0; kt < 2; kt++) {
            short8 a = *(const short8*)(H2 + (mt * 16 + l15) * 72 + kt * 32 + lq * 8);
            acc = __builtin_amdgcn_mfma_f32_16x16x32_bf16(a, t1f[kt], acc, 0, 0, 0);
        }
#pragma unroll
        for (int r = 0; r < 4; r++)
            XF[(mt * 16 + lq * 4 + r) * 65 + w * 16 + l15] =
                fmaxf(acc[r] + tb1v, 0.f);
    }
    ldsbar();
    float s0 = tb2[2 * w], s1 = tb2[2 * w + 1];
    for (int k = 0; k < 64; k++) {
        float xk = XF[l * 65 + k];
        float2 wp = *(const float2*)(tw2 + k * 8 + 2 * w);
        s0 = fmaf(xk, wp.x, s0);
        s1 = fmaf(xk, wp.y, s1);
    }
    if (blk0 + l < n_nodes) {
        float2 r;
        r.x = 1.f / (1.f + __expf(-s0));
        r.y = 1.f / (1.f + __expf(-s1));
        *(float2*)(out + (size_t)(blk0 + l) * 8 + 2 * w) = r;
    }
}

// ---------------------------------------------------------------------------
// Edge conv, R9: CSR dest-range blocks + LDS accumulator (R8 structure) with
// the LDS-atomic fix: register run-reduce over each lane-quad's 4 sorted
// rows, then NATIVE ds_add_f32 (__hip_atomic_fetch_add, workgroup scope) --
// ~1.2 emissions per quad instead of 16 CAS-loop atomics per thread.
// 2 barriers/tile; zero global atomics; coalesced flush covers all dests.
// LDS = 21504(A) + 9216(Hs) + 256(Didx) + 8192(acc) = 39168 B -> 4 blk/CU.
// ---------------------------------------------------------------------------
#define AROW 168
#define HROW 72
#define DPB 32

__global__ __launch_bounds__(256, 4) void edge_conv(
    const u16* __restrict__ u_feat, const u16* __restrict__ v_feat,
    const int4* __restrict__ epk,      // full packed edge array (both sides)
    const int* __restrict__ cursor,    // CSR end-offsets, concatenated dests
    int gd_base, int ndst,             // global dest base, #dests this side
    const u16* __restrict__ w1s, const u16* __restrict__ w2s,
    const float* __restrict__ b1, const float* __restrict__ b2,
    float* __restrict__ agg) {
    __shared__ __align__(16) u16 A[64 * AROW];
    __shared__ __align__(16) u16 Hs[64 * HROW];
    __shared__ int Didx[64];           // local dest per row, -1 = pad
    __shared__ __align__(16) float accs[DPB * 64];

    int tid = threadIdx.x;
    int lane = tid & 63;
    int w = tid >> 6;
    int l15 = lane & 15, lq = lane >> 4;
    int cch = tid & 15, e0row = tid >> 4;

    int d0s = (int)blockIdx.x * DPB;       // side-local dest base
    if (d0s >= ndst) return;
    int nloc = ndst - d0s; if (nloc > DPB) nloc = DPB;
    int gd0 = gd_base + d0s;
    int e0 = (gd0 == 0) ? 0 : cursor[gd0 - 1];
    int e1 = cursor[gd0 + nloc - 1];

    // zero acc + zero pad cols [129,168)
    for (int i = tid; i < DPB * 64; i += 256) accs[i] = 0.f;
    for (int i = tid; i < 64 * (AROW - 129); i += 256) {
        int r = i / (AROW - 129);
        int cc = 129 + (i - r * (AROW - 129));
        A[r * AROW + cc] = 0;
    }

    short8 w1f[5], w2f[2];
#pragma unroll
    for (int kt = 0; kt < 5; kt++)
        w1f[kt] = *(const short8*)(w1s + ((w * 5 + kt) * 64 + lane) * 8);
#pragma unroll
    for (int kt = 0; kt < 2; kt++)
        w2f[kt] = *(const short8*)(w2s + ((w * 2 + kt) * 64 + lane) * 8);
    float b1v = b1[w * 16 + l15];
    float b2v = b2[w * 16 + l15];

    const bool fsel = (cch < 8);
    const u16* fbase = fsel ? u_feat : v_feat;
    const int gcol = fsel ? cch * 8 : 64 + (cch - 8) * 8;
    const int coff = (cch & 7) * 8;
    const int* epki = (const int*)epk;

    int ntl = (e1 - e0 + 63) >> 6;         // tiles in this block's range

    uint4 st[4];   // staged features, current tile
    u32 evb[4];    // e_val bits, current tile
    int4 pe[4];    // packed edges, NEXT tile
    int ddx = -1, ddx_n = -1;

    if (ntl > 0) {
        // prologue: stage tile 0 directly, prefetch epk of tile 1
#pragma unroll
        for (int t = 0; t < 4; t++) {
            int le = e0 + e0row + t * 16; if (le >= e1) le = e1 - 1;
            int4 e = epk[le];
            int ix = fsel ? e.x : e.y;
            st[t] = *(const uint4*)(fbase + (size_t)ix * 64 + coff);
            evb[t] = (u32)e.z;
        }
        if (tid < 64) {
            int le = e0 + tid;
            ddx = (le < e1) ? (epki[le * 4] - d0s) : -1;
        }
        if (ntl > 1) {
            int b2b = e0 + 64;
#pragma unroll
            for (int t = 0; t < 4; t++) {
                int le = b2b + e0row + t * 16; if (le >= e1) le = e1 - 1;
                pe[t] = epk[le];
            }
            if (tid < 64) {
                int le = b2b + tid;
                ddx_n = (le < e1) ? (epki[le * 4] - d0s) : -1;
            }
        }
    }

    for (int tl = 0; tl < ntl; ++tl) {
        // commit staged regs to LDS (cols 0..128) + local dest ids
#pragma unroll
        for (int t = 0; t < 4; t++) {
            int e = e0row + t * 16;
            *(uint4*)(&A[e * AROW + gcol]) = st[t];
            if (cch == 0) A[e * AROW + 128] = bf16rne(__uint_as_float(evb[t]));
        }
        if (tid < 64) Didx[tid] = ddx;
        // pipeline: gather tile+1 features (epk in regs), prefetch epk tile+2
        if (tl + 1 < ntl) {
#pragma unroll
            for (int t = 0; t < 4; t++) {
                int ix = fsel ? pe[t].x : pe[t].y;
                st[t] = *(const uint4*)(fbase + (size_t)ix * 64 + coff);
                evb[t] = (u32)pe[t].z;
            }
            ddx = ddx_n;
            if (tl + 2 < ntl) {
                int b2b = e0 + (tl + 2) * 64;
#pragma unroll
                for (int t = 0; t < 4; t++) {
                    int le = b2b + e0row + t * 16; if (le >= e1) le = e1 - 1;
                    pe[t] = epk[le];
                }
                if (tid < 64) {
                    int le = b2b + tid;
                    ddx_n = (le < e1) ? (epki[le * 4] - d0s) : -1;
                }
            }
        }
        ldsbar();  // B1: A + Didx staged (also: prev L1's A reads done)

#pragma unroll
        for (int mt = 0; mt < 4; mt++) {
            short8 a1[5];
#pragma unroll
            for (int kt = 0; kt < 5; kt++)
                a1[kt] = *(const short8*)(&A[(mt * 16 + l15) * AROW + kt * 32 + lq * 8]);
            f32x4 acc = {0.f, 0.f, 0.f, 0.f};
#pragma unroll
            for (int kt = 0; kt < 5; kt++)
                acc = __builtin_amdgcn_mfma_f32_16x16x32_bf16(a1[kt], w1f[kt], acc, 0, 0, 0);
#pragma unroll
            for (int r = 0; r < 4; r++) {
                float hv = fmaxf(acc[r] + b1v, 0.f);
                Hs[(mt * 16 + lq * 4 + r) * HROW + w * 16 + l15] = bf16rne(hv);
            }
        }
        ldsbar();  // B2: Hs ready (also: prev L2's Hs reads done)

        // L2 MFMA + register run-reduce over the quad's 4 sorted rows, then
        // native ds_add_f32 emissions (~1.2 per quad instead of 4).
#pragma unroll
        for (int mt = 0; mt < 4; mt++) {
            short8 a2[2];
#pragma unroll
            for (int kt = 0; kt < 2; kt++)
                a2[kt] = *(const short8*)(&Hs[(mt * 16 + l15) * HROW + kt * 32 + lq * 8]);
            f32x4 acc = {0.f, 0.f, 0.f, 0.f};
#pragma unroll
            for (int kt = 0; kt < 2; kt++)
                acc = __builtin_amdgcn_mfma_f32_16x16x32_bf16(a2[kt], w2f[kt], acc, 0, 0, 0);
            int row0 = mt * 16 + lq * 4;
            int dcur = Didx[row0];
            float s = fmaxf(acc[0] + b2v, 0.f);
#pragma unroll
            for (int r = 1; r < 4; r++) {
                int d = Didx[row0 + r];
                float gv = fmaxf(acc[r] + b2v, 0.f);
                if (d == dcur) {
                    s += gv;
                } else {
                    if (dcur >= 0) ds_addf(&accs[dcur * 64 + w * 16 + l15], s);
                    dcur = d;
                    s = gv;
                }
            }
            if (dcur >= 0) ds_addf(&accs[dcur * 64 + w * 16 + l15], s);
        }
    }

    ldsbar();  // all ds_adds visible
    // coalesced flush: every dest in [d0s, d0s+nloc) written exactly once
    for (int i = tid * 4; i < nloc * 64; i += 1024)
        *(float4*)(agg + (size_t)d0s * 64 + i) = *(const float4*)(accs + i);
}

extern "C" void kernel_launch(void* const* d_in, const int* in_sizes, int n_in,
                              void* d_out, int out_size, void* d_ws, size_t ws_size,
                              hipStream_t stream) {
    const float* v        = (const float*)d_in[0];
    const float* c        = (const float*)d_in[1];
    const int*   cons_idx = (const int*)d_in[2];
    const int*   var_idx  = (const int*)d_in[3];
    const float* e_val    = (const float*)d_in[4];
    const float* ev_w1 = (const float*)d_in[5],  *ev_b1 = (const float*)d_in[6];
    const float* ev_w2 = (const float*)d_in[7],  *ev_b2 = (const float*)d_in[8];
    const float* ec_w1 = (const float*)d_in[9],  *ec_b1 = (const float*)d_in[10];
    const float* ec_w2 = (const float*)d_in[11], *ec_b2 = (const float*)d_in[12];
    const float* cg_w1 = (const float*)d_in[13], *cg_b1 = (const float*)d_in[14];
    const float* cg_w2 = (const float*)d_in[15], *cg_b2 = (const float*)d_in[16];
    const float* cf_w1 = (const float*)d_in[17], *cf_b1 = (const float*)d_in[18];
    const float* cf_w2 = (const float*)d_in[19], *cf_b2 = (const float*)d_in[20];
    const float* vg_w1 = (const float*)d_in[21], *vg_b1 = (const float*)d_in[22];
    const float* vg_w2 = (const float*)d_in[23], *vg_b2 = (const float*)d_in[24];
    const float* vf_w1 = (const float*)d_in[25], *vf_b1 = (const float*)d_in[26];
    const float* vf_w2 = (const float*)d_in[27], *vf_b2 = (const float*)d_in[28];
    const float* t_w1  = (const float*)d_in[29], *t_b1  = (const float*)d_in[30];
    const float* t_w2  = (const float*)d_in[31], *t_b2  = (const float*)d_in[32];

    const int NV = in_sizes[0] / 19;
    const int NC = in_sizes[1] / 5;
    const int NE = in_sizes[4];

    char* ws = (char*)d_ws;
    size_t off = 0;
    u16* v1bf = (u16*)(ws + off); off += (size_t)NV * 64 * 2;
    u16* c1bf = (u16*)(ws + off); off += (size_t)NC * 64 * 2;
    u16* c2bf = (u16*)(ws + off); off += (size_t)NC * 64 * 2;
    float* agg_c = (float*)(ws + off); off += (size_t)NC * 64 * 4;
    float* agg_v = (float*)(ws + off); off += (size_t)NV * 64 * 4;
    u16* ev1s = (u16*)(ws + off); off += 2048 * 2;
    u16* ev2s = (u16*)(ws + off); off += 4096 * 2;
    u16* ec1s = (u16*)(ws + off); off += 2048 * 2;
    u16* ec2s = (u16*)(ws + off); off += 4096 * 2;
    u16* cg1s = (u16*)(ws + off); off += 10240 * 2;
    u16* cg2s = (u16*)(ws + off); off += 4096 * 2;
    u16* cf1s = (u16*)(ws + off); off += 8192 * 2;
    u16* cf2s = (u16*)(ws + off); off += 4096 * 2;
    u16* vg1s = (u16*)(ws + off); off += 10240 * 2;
    u16* vg2s = (u16*)(ws + off); off += 4096 * 2;
    u16* vf1s = (u16*)(ws + off); off += 8192 * 2;
    u16* vf2s = (u16*)(ws + off); off += 4096 * 2;
    u16* t1s  = (u16*)(ws + off); off += 4096 * 2;
    off = (off + 255) & ~(size_t)255;
    int* cnt    = (int*)(ws + off); off += (size_t)(NC + NV) * 4;
    int* cursor = (int*)(ws + off); off += (size_t)(NC + NV) * 4;
    int* bsum   = (int*)(ws + off); off += 64 * 4;
    off = (off + 255) & ~(size_t)255;
    int4* epk   = (int4*)(ws + off); off += (size_t)NE * 2 * 16;

    const int nd = NC + NV;
    const int nb = (nd + SCAN_CHUNK - 1) / SCAN_CHUNK;

    prep_weights<<<40, 256, 0, stream>>>(
        ev_w1, ev_w2, ec_w1, ec_w2, cg_w1, cg_w2, cf_w1, cf_w2,
        vg_w1, vg_w2, vf_w1, vf_w2, t_w1,
        ev1s, ev2s, ec1s, ec2s, cg1s, cg2s, cf1s, cf2s,
        vg1s, vg2s, vf1s, vf2s, t1s);

    // fused dual counting sort (c positions in [0,NE), v in [NE,2NE))
    hipMemsetAsync(cnt, 0, (size_t)nd * 4, stream);
    hist2<<<512, 256, 0, stream>>>(cons_idx, var_idx, NE, NC, cnt);
    scan_part<<<nb, 256, 0, stream>>>(cnt, nd, bsum);
    scan_bsum<<<1, 64, 0, stream>>>(bsum, nb);
    scan_final<<<nb, 256, 0, stream>>>(cnt, nd, bsum, cursor);
    scatter2<<<1024, 256, 0, stream>>>(cons_idx, var_idx, e_val, NE, NC,
                                       cursor, epk);

    node_mlp_in<19><<<(NV + 63) / 64, 256, 0, stream>>>(
        v, NV, ev1s, ev_b1, ev2s, ev_b2, v1bf);
    node_mlp_in<5><<<(NC + 63) / 64, 256, 0, stream>>>(
        c, NC, ec1s, ec_b1, ec2s, ec_b2, c1bf);

    // c-side conv + f-MLP (no agg memset: flush covers all dests)
    edge_conv<<<(NC + DPB - 1) / DPB, 256, 0, stream>>>(
        c1bf, v1bf, epk, cursor, 0, NC,
        cg1s, cg2s, cg_b1, cg_b2, agg_c);
    node_mlp_f<<<(NC + 63) / 64, 256, 0, stream>>>(
        c1bf, agg_c, NC, cf1s, cf_b1, cf2s, cf_b2, c2bf);

    // v-side conv + f-MLP + tail
    edge_conv<<<(NV + DPB - 1) / DPB, 256, 0, stream>>>(
        v1bf, c2bf, epk, cursor, NC, NV,
        vg1s, vg2s, vg_b1, vg_b2, agg_v);
    node_mlp_vf_tail<<<(NV + 63) / 64, 256, 0, stream>>>(
        v1bf, agg_v, NV, vf1s, vf_b1, vf2s, vf_b2,
        t1s, t_b1, t_w2, t_b2, (float*)d_out);
}

// Round 6
// 530.291 us; speedup vs baseline: 2.4603x; 1.5564x over previous
//
#include <hip/hip_runtime.h>
#include <hip/hip_bf16.h>

typedef short short8 __attribute__((ext_vector_type(8)));
typedef float f32x4 __attribute__((ext_vector_type(4)));
typedef unsigned short u16;
typedef unsigned int u32;

__device__ __forceinline__ u16 bf16rne(float f) {
    u32 u = __float_as_uint(f);
    u32 r = (u + 0x7fffu + ((u >> 16) & 1u)) >> 16;
    return (u16)r;
}
__device__ __forceinline__ float bf2f(u16 s) {
    return __uint_as_float(((u32)s) << 16);
}

// LDS-only barrier: wave-sync + LDS visibility WITHOUT draining vmcnt, so
// scatter atomics and prefetch loads stay in flight across barriers.
__device__ __forceinline__ void ldsbar() {
    asm volatile("s_waitcnt lgkmcnt(0)" ::: "memory");
    __builtin_amdgcn_s_barrier();
    asm volatile("" ::: "memory");
}

// ---------------------------------------------------------------------------
// Weight swizzle into MFMA B-fragment order, bf16 (unchanged).
// ---------------------------------------------------------------------------
__device__ __forceinline__ void swz(const float* __restrict__ src,
                                    u16* __restrict__ dst, int K, int KT,
                                    int tid0, int stride) {
    int total = 4 * KT * 512;
    for (int i = tid0; i < total; i += stride) {
        int j = i & 7, lane = (i >> 3) & 63, g = i >> 9;
        int kt = g % KT;
        int k = kt * 32 + (lane >> 4) * 8 + j;
        int n = (g / KT) * 16 + (lane & 15);
        dst[i] = (k < K) ? bf16rne(src[k * 64 + n]) : (u16)0;
    }
}

__global__ void prep_weights(
    const float* ev1, const float* ev2, const float* ec1, const float* ec2,
    const float* cg1, const float* cg2, const float* cf1, const float* cf2,
    const float* vg1, const float* vg2, const float* vf1, const float* vf2,
    const float* t1,
    u16* dev1, u16* dev2, u16* dec1, u16* dec2, u16* dcg1, u16* dcg2,
    u16* dcf1, u16* dcf2, u16* dvg1, u16* dvg2, u16* dvf1, u16* dvf2,
    u16* dt1) {
    int tid0 = blockIdx.x * blockDim.x + threadIdx.x;
    int st = gridDim.x * blockDim.x;
    swz(ev1, dev1, 19, 1, tid0, st);
    swz(ev2, dev2, 64, 2, tid0, st);
    swz(ec1, dec1, 5, 1, tid0, st);
    swz(ec2, dec2, 64, 2, tid0, st);
    swz(cg1, dcg1, 129, 5, tid0, st);
    swz(cg2, dcg2, 64, 2, tid0, st);
    swz(cf1, dcf1, 128, 4, tid0, st);
    swz(cf2, dcf2, 64, 2, tid0, st);
    swz(vg1, dvg1, 129, 5, tid0, st);
    swz(vg2, dvg2, 64, 2, tid0, st);
    swz(vf1, dvf1, 128, 4, tid0, st);
    swz(vf2, dvf2, 64, 2, tid0, st);
    swz(t1, dt1, 64, 2, tid0, st);
}

// ---------------------------------------------------------------------------
// Fused counting-sort, rank-based (no scatter atomics).
// hist2: per-edge ranks from the histogram atomics' return values.
// scan: joint exclusive scan over [c-counts(NC) | v-counts(NV)] -> base[].
// scatter2: pos = base[d] + rank; writes packed epk {dst, src, ev, 0};
// c positions land in [0,NE), v positions in [NE,2NE).
// ---------------------------------------------------------------------------
#define SCAN_CHUNK 4096

__global__ void hist2(const int* __restrict__ ci, const int* __restrict__ vi,
                      int ne, int nc, int* __restrict__ cnt,
                      u32* __restrict__ ranks) {
    int i = blockIdx.x * blockDim.x + threadIdx.x;
    int st = gridDim.x * blockDim.x;
    for (; i < ne; i += st) {
        int rc = atomicAdd(&cnt[ci[i]], 1);
        int rv = atomicAdd(&cnt[nc + vi[i]], 1);
        ranks[i] = ((u32)rc & 0xffffu) | ((u32)rv << 16);
    }
}

__global__ void scan_part(const int* __restrict__ cnt, int nd,
                          int* __restrict__ bsum) {
    __shared__ int sred[256];
    int b = blockIdx.x, t = threadIdx.x;
    int base = b * SCAN_CHUNK + t * 16;
    int s = 0;
#pragma unroll
    for (int j = 0; j < 16; j++) {
        int i = base + j;
        if (i < nd) s += cnt[i];
    }
    sred[t] = s;
    __syncthreads();
    for (int o = 128; o > 0; o >>= 1) {
        if (t < o) sred[t] += sred[t + o];
        __syncthreads();
    }
    if (t == 0) bsum[b] = sred[0];
}

__global__ void scan_bsum(int* bsum, int nb) {
    if (threadIdx.x == 0 && blockIdx.x == 0) {
        int run = 0;
        for (int i = 0; i < nb; i++) {
            int v = bsum[i];
            bsum[i] = run;
            run += v;
        }
    }
}

__global__ void scan_final(const int* __restrict__ cnt, int nd,
                           const int* __restrict__ bsum,
                           int* __restrict__ basep) {
    __shared__ int sa[256];
    int b = blockIdx.x, t = threadIdx.x;
    int base = b * SCAN_CHUNK + t * 16;
    int loc[16];
    int s = 0;
#pragma unroll
    for (int j = 0; j < 16; j++) {
        int i = base + j;
        int v = (i < nd) ? cnt[i] : 0;
        loc[j] = s;
        s += v;
    }
    sa[t] = s;
    __syncthreads();
    int inc = s;
    for (int o = 1; o < 256; o <<= 1) {
        int v = (t >= o) ? sa[t - o] : 0;
        __syncthreads();
        sa[t] += v;
        __syncthreads();
    }
    int off = bsum[b] + sa[t] - inc;
#pragma unroll
    for (int j = 0; j < 16; j++) {
        int i = base + j;
        if (i < nd) basep[i] = off + loc[j];
    }
}

__global__ void scatter2(const int* __restrict__ ci, const int* __restrict__ vi,
                         const float* __restrict__ ev,
                         const u32* __restrict__ ranks, int ne, int nc,
                         const int* __restrict__ basep,
                         int4* __restrict__ epk) {
    int i = blockIdx.x * blockDim.x + threadIdx.x;
    int st = gridDim.x * blockDim.x;
    for (; i < ne; i += st) {
        int cd = ci[i], vd = vi[i];
        u32 rk = ranks[i];
        int eb = __float_as_int(ev[i]);
        int pc = basep[cd] + (int)(rk & 0xffffu);
        int pv = basep[nc + vd] + (int)(rk >> 16);
        epk[pc] = make_int4(cd, vd, eb, 0);
        epk[pv] = make_int4(vd, cd, eb, 0);
    }
}

// ---------------------------------------------------------------------------
// Generic MFMA layer (unchanged).
// ---------------------------------------------------------------------------
template <int KT, int SA>
__device__ __forceinline__ void mfma_layer(const u16* __restrict__ Asrc,
                                           const short8* wf, float bv,
                                           u16* __restrict__ Hdst,
                                           int l15, int lq, int w) {
#pragma unroll
    for (int mt = 0; mt < 4; mt++) {
        f32x4 acc = {0.f, 0.f, 0.f, 0.f};
#pragma unroll
        for (int kt = 0; kt < KT; kt++) {
            short8 a = *(const short8*)(Asrc + (mt * 16 + l15) * SA + kt * 32 + lq * 8);
            acc = __builtin_amdgcn_mfma_f32_16x16x32_bf16(a, wf[kt], acc, 0, 0, 0);
        }
#pragma unroll
        for (int r = 0; r < 4; r++)
            Hdst[(mt * 16 + lq * 4 + r) * 72 + w * 16 + l15] =
                bf16rne(fmaxf(acc[r] + bv, 0.f));
    }
}

// ---------------------------------------------------------------------------
// Input node MLP (unchanged).
// ---------------------------------------------------------------------------
template <int KIN>
__global__ __launch_bounds__(256, 6) void node_mlp_in(
    const float* __restrict__ x, int n_nodes,
    const u16* __restrict__ w1s, const float* __restrict__ b1,
    const u16* __restrict__ w2s, const float* __restrict__ b2,
    u16* __restrict__ outbf) {
    __shared__ __align__(16) u16 A[64 * 40];
    __shared__ __align__(16) u16 H1[64 * 72];
    __shared__ __align__(16) u16 H2[64 * 72];
    int tid = threadIdx.x, l = tid & 63, w = tid >> 6;
    int l15 = l & 15, lq = l >> 4;
    int blk0 = blockIdx.x * 64;
    const int PW = 40 - KIN;
    for (int i = tid; i < 64 * PW; i += 256) {
        int r = i / PW, cc = KIN + (i - r * PW);
        A[r * 40 + cc] = 0;
    }
    for (int i = tid; i < 64 * KIN; i += 256) {
        int r = i / KIN, k = i - r * KIN;
        int gn = blk0 + r; if (gn >= n_nodes) gn = n_nodes - 1;
        A[r * 40 + k] = bf16rne(x[(size_t)gn * KIN + k]);
    }
    short8 w1f[1], w2f[2];
    w1f[0] = *(const short8*)(w1s + ((w * 1 + 0) * 64 + l) * 8);
#pragma unroll
    for (int kt = 0; kt < 2; kt++)
        w2f[kt] = *(const short8*)(w2s + ((w * 2 + kt) * 64 + l) * 8);
    float b1v = b1[w * 16 + l15], b2v = b2[w * 16 + l15];
    ldsbar();
    mfma_layer<1, 40>(A, w1f, b1v, H1, l15, lq, w);
    ldsbar();
    mfma_layer<2, 72>(H1, w2f, b2v, H2, l15, lq, w);
    ldsbar();
    for (int i = tid; i < 512; i += 256) {
        int r = i >> 3, c = i & 7;
        if (blk0 + r < n_nodes)
            *(uint4*)(outbf + (size_t)(blk0 + r) * 64 + c * 8) =
                *(const uint4*)(H2 + r * 72 + c * 8);
    }
}

// ---------------------------------------------------------------------------
// f-MLP staging (unchanged).
// ---------------------------------------------------------------------------
__device__ __forceinline__ void stage_concat_res(
    const u16* __restrict__ ubf, const float* __restrict__ agg,
    int blk0, int n_nodes, u16* __restrict__ A, int tid) {
    for (int i = tid; i < 64 * 24; i += 256) {
        int nd = i / 24, c = i - nd * 24;
        int gn = blk0 + nd; if (gn >= n_nodes) gn = n_nodes - 1;
        if (c < 8) {
            *(uint4*)(A + nd * 200 + c * 8) =
                *(const uint4*)(ubf + (size_t)gn * 64 + c * 8);
        } else {
            int q = c - 8;
            float4 av = *(const float4*)(agg + (size_t)gn * 64 + q * 4);
            u16 h0 = bf16rne(av.x), h1 = bf16rne(av.y);
            u16 h2 = bf16rne(av.z), h3 = bf16rne(av.w);
            uint2 hi;
            hi.x = (u32)h0 | ((u32)h1 << 16);
            hi.y = (u32)h2 | ((u32)h3 << 16);
            *(uint2*)(A + nd * 200 + 64 + q * 4) = hi;
            uint2 rs;
            rs.x = (u32)bf16rne(av.x - bf2f(h0)) | ((u32)bf16rne(av.y - bf2f(h1)) << 16);
            rs.y = (u32)bf16rne(av.z - bf2f(h2)) | ((u32)bf16rne(av.w - bf2f(h3)) << 16);
            *(uint2*)(A + nd * 200 + 128 + q * 4) = rs;
        }
    }
}

// ---------------------------------------------------------------------------
// c-side f-MLP (unchanged).
// ---------------------------------------------------------------------------
__global__ __launch_bounds__(256, 4) void node_mlp_f(
    const u16* __restrict__ ubf, const float* __restrict__ agg, int n_nodes,
    const u16* __restrict__ w1s, const float* __restrict__ b1,
    const u16* __restrict__ w2s, const float* __restrict__ b2,
    u16* __restrict__ outbf) {
    __shared__ __align__(16) u16 A[64 * 200];
    __shared__ __align__(16) u16 H1[64 * 72];
    int tid = threadIdx.x, l = tid & 63, w = tid >> 6;
    int l15 = l & 15, lq = l >> 4;
    int blk0 = blockIdx.x * 64;
    stage_concat_res(ubf, agg, blk0, n_nodes, A, tid);
    short8 w1f[6], w2f[2];
#pragma unroll
    for (int kt = 0; kt < 4; kt++)
        w1f[kt] = *(const short8*)(w1s + ((w * 4 + kt) * 64 + l) * 8);
    w1f[4] = w1f[2];
    w1f[5] = w1f[3];
#pragma unroll
    for (int kt = 0; kt < 2; kt++)
        w2f[kt] = *(const short8*)(w2s + ((w * 2 + kt) * 64 + l) * 8);
    float b1v = b1[w * 16 + l15], b2v = b2[w * 16 + l15];
    ldsbar();
    mfma_layer<6, 200>(A, w1f, b1v, H1, l15, lq, w);
    ldsbar();
    mfma_layer<2, 72>(H1, w2f, b2v, A, l15, lq, w);
    ldsbar();
    for (int i = tid; i < 512; i += 256) {
        int r = i >> 3, c = i & 7;
        if (blk0 + r < n_nodes)
            *(uint4*)(outbf + (size_t)(blk0 + r) * 64 + c * 8) =
                *(const uint4*)(A + r * 72 + c * 8);
    }
}

// ---------------------------------------------------------------------------
// v-side f-MLP + tail (unchanged).
// ---------------------------------------------------------------------------
__global__ __launch_bounds__(256, 3) void node_mlp_vf_tail(
    const u16* __restrict__ vbf, const float* __restrict__ agg, int n_nodes,
    const u16* __restrict__ w1s, const float* __restrict__ b1,
    const u16* __restrict__ w2s, const float* __restrict__ b2,
    const u16* __restrict__ t1s, const float* __restrict__ tb1,
    const float* __restrict__ tw2, const float* __restrict__ tb2,
    float* __restrict__ out) {
    __shared__ __align__(16) char smem[64 * 200 * 2 + 2 * 64 * 72 * 2];
    u16* A = (u16*)smem;
    float* XF = (float*)smem;
    u16* H1 = (u16*)(smem + 25600);
    u16* H2 = (u16*)(smem + 25600 + 9216);
    int tid = threadIdx.x, l = tid & 63, w = tid >> 6;
    int l15 = l & 15, lq = l >> 4;
    int blk0 = blockIdx.x * 64;
    stage_concat_res(vbf, agg, blk0, n_nodes, A, tid);
    short8 w1f[6], w2f[2], t1f[2];
#pragma unroll
    for (int kt = 0; kt < 4; kt++)
        w1f[kt] = *(const short8*)(w1s + ((w * 4 + kt) * 64 + l) * 8);
    w1f[4] = w1f[2];
    w1f[5] = w1f[3];
#pragma unroll
    for (int kt = 0; kt < 2; kt++) {
        w2f[kt] = *(const short8*)(w2s + ((w * 2 + kt) * 64 + l) * 8);
        t1f[kt] = *(const short8*)(t1s + ((w * 2 + kt) * 64 + l) * 8);
    }
    float b1v = b1[w * 16 + l15], b2v = b2[w * 16 + l15];
    float tb1v = tb1[w * 16 + l15];
    ldsbar();
    mfma_layer<6, 200>(A, w1f, b1v, H1, l15, lq, w);
    ldsbar();
    mfma_layer<2, 72>(H1, w2f, b2v, H2, l15, lq, w);
    ldsbar();
#pragma unroll
    for (int mt = 0; mt < 4; mt++) {
        f32x4 acc = {0.f, 0.f, 0.f, 0.f};
#pragma unroll
        for (int kt = 0; kt < 2; kt++) {
            short8 a = *(const short8*)(H2 + (mt * 16 + l15) * 72 + kt * 32 + lq * 8);
            acc = __builtin_amdgcn_mfma_f32_16x16x32_bf16(a, t1f[kt], acc, 0, 0, 0);
        }
#pragma unroll
        for (int r = 0; r < 4; r++)
            XF[(mt * 16 + lq * 4 + r) * 65 + w * 16 + l15] =
                fmaxf(acc[r] + tb1v, 0.f);
    }
    ldsbar();
    float s0 = tb2[2 * w], s1 = tb2[2 * w + 1];
    for (int k = 0; k < 64; k++) {
        float xk = XF[l * 65 + k];
        float2 wp = *(const float2*)(tw2 + k * 8 + 2 * w);
        s0 = fmaf(xk, wp.x, s0);
        s1 = fmaf(xk, wp.y, s1);
    }
    if (blk0 + l < n_nodes) {
        float2 r;
        r.x = 1.f / (1.f + __expf(-s0));
        r.y = 1.f / (1.f + __expf(-s1));
        *(float2*)(out + (size_t)(blk0 + l) * 8 + 2 * w) = r;
    }
}

// ---------------------------------------------------------------------------
// Edge conv: R2's proven structure (116 us/dispatch), epk-adapted.
// Grid-stride 1280 blocks, 4 ldsbars/tile, Gf staged into the dead A region,
// 256-thread segmented reduce (thread t scans rows [16*(t>>6),+16) of column
// t&63), wave-coalesced global atomics (~7e6 lanes). 5 blocks/CU.
// ---------------------------------------------------------------------------
#define AROW 168
#define HROW 72

__global__ __launch_bounds__(256, 5) void edge_conv(
    const u16* __restrict__ u_feat, const u16* __restrict__ v_feat,
    const int4* __restrict__ epk,   // sorted packed edges {dst, src, ev, 0}
    const u16* __restrict__ w1s, const u16* __restrict__ w2s,
    const float* __restrict__ b1, const float* __restrict__ b2,
    float* __restrict__ agg, int n_tiles) {
    __shared__ __align__(16) u16 A[64 * AROW];   // staging; later G (f32) overlay
    __shared__ __align__(16) u16 Hs[64 * HROW];
    __shared__ int Didx[64];

    int tid = threadIdx.x;
    int lane = tid & 63;
    int w = tid >> 6;
    int l15 = lane & 15, lq = lane >> 4;
    int cch = tid & 15, e0 = tid >> 4;

    // zero pad cols [129,168) once; staging rewrites cols [0,129), G overlay
    // touches only f32 cols [0,64).
    for (int i = tid; i < 64 * (AROW - 129); i += 256) {
        int r = i / (AROW - 129);
        int cc = 129 + (i - r * (AROW - 129));
        A[r * AROW + cc] = 0;
    }

    short8 w1f[5], w2f[2];
#pragma unroll
    for (int kt = 0; kt < 5; kt++)
        w1f[kt] = *(const short8*)(w1s + ((w * 5 + kt) * 64 + lane) * 8);
#pragma unroll
    for (int kt = 0; kt < 2; kt++)
        w2f[kt] = *(const short8*)(w2s + ((w * 2 + kt) * 64 + lane) * 8);
    float b1v = b1[w * 16 + l15];
    float b2v = b2[w * 16 + l15];

    const bool fsel = (cch < 8);
    const u16* fbase = fsel ? u_feat : v_feat;
    const int gcol = fsel ? cch * 8 : 64 + (cch - 8) * 8;
    const int coff = (cch & 7) * 8;
    const int* epki = (const int*)epk;

    const int G = gridDim.x;
    int tile = (int)blockIdx.x;

    uint4 st[4];   // staged features for current tile (loaded 1 iter ahead)
    u32 evb[4];    // e_val bits, current tile
    int4 pe[4];    // packed edges for NEXT tile (loaded 2 iters ahead)
    int didx_c = 0, didx_n = 0;

    if (tile < n_tiles) {
#pragma unroll
        for (int t = 0; t < 4; t++) {
            int ge = tile * 64 + e0 + t * 16;
            int4 e = epk[ge];
            int ix = fsel ? e.x : e.y;
            st[t] = *(const uint4*)(fbase + (size_t)ix * 64 + coff);
            evb[t] = (u32)e.z;
        }
        if (tid < 64) didx_c = epki[(tile * 64 + tid) * 4];
        int ntp = tile + G;
        if (ntp < n_tiles) {
#pragma unroll
            for (int t = 0; t < 4; t++) pe[t] = epk[ntp * 64 + e0 + t * 16];
        }
    }

    for (; tile < n_tiles; tile += G) {
        ldsbar();  // B0: prev seg-reduce reads of G done before commit writes
#pragma unroll
        for (int t = 0; t < 4; t++) {
            int e = e0 + t * 16;
            *(uint4*)(&A[e * AROW + gcol]) = st[t];
            if (cch == 0) A[e * AROW + 128] = bf16rne(__uint_as_float(evb[t]));
        }
        // issue next tile's gathers (epk already in regs) and the
        // tile-after-next's epk loads; all overlap B1+L1+B2+L2
        int nt = tile + G;
        if (nt < n_tiles) {
#pragma unroll
            for (int t = 0; t < 4; t++) {
                int ix = fsel ? pe[t].x : pe[t].y;
                st[t] = *(const uint4*)(fbase + (size_t)ix * 64 + coff);
                evb[t] = (u32)pe[t].z;
            }
            if (tid < 64) didx_n = epki[(nt * 64 + tid) * 4];
            int nt2 = nt + G;
            if (nt2 < n_tiles) {
#pragma unroll
                for (int t = 0; t < 4; t++)
                    pe[t] = epk[nt2 * 64 + e0 + t * 16];
            }
        }
        ldsbar();  // B1: A staged (LDS only; atomics/prefetch stay in flight)

#pragma unroll
        for (int mt = 0; mt < 4; mt++) {
            short8 a1[5];
#pragma unroll
            for (int kt = 0; kt < 5; kt++)
                a1[kt] = *(const short8*)(&A[(mt * 16 + l15) * AROW + kt * 32 + lq * 8]);
            f32x4 acc = {0.f, 0.f, 0.f, 0.f};
#pragma unroll
            for (int kt = 0; kt < 5; kt++)
                acc = __builtin_amdgcn_mfma_f32_16x16x32_bf16(a1[kt], w1f[kt], acc, 0, 0, 0);
#pragma unroll
            for (int r = 0; r < 4; r++) {
                float hv = fmaxf(acc[r] + b1v, 0.f);
                Hs[(mt * 16 + lq * 4 + r) * HROW + w * 16 + l15] = bf16rne(hv);
            }
        }
        ldsbar();  // B2: Hs ready; A reads done -> A region free for G

        float* Gf = (float*)A;  // row stride 84 floats; cols 0..63 used
#pragma unroll
        for (int mt = 0; mt < 4; mt++) {
            short8 a2[2];
#pragma unroll
            for (int kt = 0; kt < 2; kt++)
                a2[kt] = *(const short8*)(&Hs[(mt * 16 + l15) * HROW + kt * 32 + lq * 8]);
            f32x4 acc = {0.f, 0.f, 0.f, 0.f};
#pragma unroll
            for (int kt = 0; kt < 2; kt++)
                acc = __builtin_amdgcn_mfma_f32_16x16x32_bf16(a2[kt], w2f[kt], acc, 0, 0, 0);
#pragma unroll
            for (int r = 0; r < 4; r++)
                Gf[(mt * 16 + lq * 4 + r) * 84 + w * 16 + l15] =
                    fmaxf(acc[r] + b2v, 0.f);
        }
        if (tid < 64) Didx[tid] = didx_c;
        ldsbar();  // B3: G + Didx ready

        // segmented reduce: thread t scans rows [16*(t>>6), +16) of col t&63.
        // Rows are destination-sorted; branch is wave-uniform; each atomic is
        // a full-wave 64-lane op on 256 contiguous bytes.
        {
            int col = tid & 63, rg = tid >> 6;
            int r0 = rg * 16;
            int dcur = Didx[r0];
            float s = Gf[r0 * 84 + col];
#pragma unroll
            for (int r = 1; r < 16; r++) {
                int d = Didx[r0 + r];
                float g = Gf[(r0 + r) * 84 + col];
                if (d != dcur) {
                    __hip_atomic_fetch_add(&agg[(size_t)dcur * 64 + col], s,
                                           __ATOMIC_RELAXED, __HIP_MEMORY_SCOPE_AGENT);
                    dcur = d;
                    s = g;
                } else {
                    s += g;
                }
            }
            __hip_atomic_fetch_add(&agg[(size_t)dcur * 64 + col], s,
                                   __ATOMIC_RELAXED, __HIP_MEMORY_SCOPE_AGENT);
        }
        didx_c = didx_n;
    }
}

extern "C" void kernel_launch(void* const* d_in, const int* in_sizes, int n_in,
                              void* d_out, int out_size, void* d_ws, size_t ws_size,
                              hipStream_t stream) {
    const float* v        = (const float*)d_in[0];
    const float* c        = (const float*)d_in[1];
    const int*   cons_idx = (const int*)d_in[2];
    const int*   var_idx  = (const int*)d_in[3];
    const float* e_val    = (const float*)d_in[4];
    const float* ev_w1 = (const float*)d_in[5],  *ev_b1 = (const float*)d_in[6];
    const float* ev_w2 = (const float*)d_in[7],  *ev_b2 = (const float*)d_in[8];
    const float* ec_w1 = (const float*)d_in[9],  *ec_b1 = (const float*)d_in[10];
    const float* ec_w2 = (const float*)d_in[11], *ec_b2 = (const float*)d_in[12];
    const float* cg_w1 = (const float*)d_in[13], *cg_b1 = (const float*)d_in[14];
    const float* cg_w2 = (const float*)d_in[15], *cg_b2 = (const float*)d_in[16];
    const float* cf_w1 = (const float*)d_in[17], *cf_b1 = (const float*)d_in[18];
    const float* cf_w2 = (const float*)d_in[19], *cf_b2 = (const float*)d_in[20];
    const float* vg_w1 = (const float*)d_in[21], *vg_b1 = (const float*)d_in[22];
    const float* vg_w2 = (const float*)d_in[23], *vg_b2 = (const float*)d_in[24];
    const float* vf_w1 = (const float*)d_in[25], *vf_b1 = (const float*)d_in[26];
    const float* vf_w2 = (const float*)d_in[27], *vf_b2 = (const float*)d_in[28];
    const float* t_w1  = (const float*)d_in[29], *t_b1  = (const float*)d_in[30];
    const float* t_w2  = (const float*)d_in[31], *t_b2  = (const float*)d_in[32];

    const int NV = in_sizes[0] / 19;
    const int NC = in_sizes[1] / 5;
    const int NE = in_sizes[4];

    char* ws = (char*)d_ws;
    size_t off = 0;
    u16* v1bf = (u16*)(ws + off); off += (size_t)NV * 64 * 2;
    u16* c1bf = (u16*)(ws + off); off += (size_t)NC * 64 * 2;
    u16* c2bf = (u16*)(ws + off); off += (size_t)NC * 64 * 2;
    float* agg_c = (float*)(ws + off); off += (size_t)NC * 64 * 4;
    float* agg_v = (float*)(ws + off); off += (size_t)NV * 64 * 4;
    u16* ev1s = (u16*)(ws + off); off += 2048 * 2;
    u16* ev2s = (u16*)(ws + off); off += 4096 * 2;
    u16* ec1s = (u16*)(ws + off); off += 2048 * 2;
    u16* ec2s = (u16*)(ws + off); off += 4096 * 2;
    u16* cg1s = (u16*)(ws + off); off += 10240 * 2;
    u16* cg2s = (u16*)(ws + off); off += 4096 * 2;
    u16* cf1s = (u16*)(ws + off); off += 8192 * 2;
    u16* cf2s = (u16*)(ws + off); off += 4096 * 2;
    u16* vg1s = (u16*)(ws + off); off += 10240 * 2;
    u16* vg2s = (u16*)(ws + off); off += 4096 * 2;
    u16* vf1s = (u16*)(ws + off); off += 8192 * 2;
    u16* vf2s = (u16*)(ws + off); off += 4096 * 2;
    u16* t1s  = (u16*)(ws + off); off += 4096 * 2;
    off = (off + 255) & ~(size_t)255;
    int* cnt    = (int*)(ws + off); off += (size_t)(NC + NV) * 4;
    int* basep  = (int*)(ws + off); off += (size_t)(NC + NV) * 4;
    int* bsum   = (int*)(ws + off); off += 64 * 4;
    off = (off + 255) & ~(size_t)255;
    u32* ranks  = (u32*)(ws + off); off += (size_t)NE * 4;
    off = (off + 255) & ~(size_t)255;
    int4* epk   = (int4*)(ws + off); off += (size_t)NE * 2 * 16;

    const int n_tiles = NE / 64;
    const int nd = NC + NV;
    const int nb = (nd + SCAN_CHUNK - 1) / SCAN_CHUNK;

    prep_weights<<<40, 256, 0, stream>>>(
        ev_w1, ev_w2, ec_w1, ec_w2, cg_w1, cg_w2, cf_w1, cf_w2,
        vg_w1, vg_w2, vf_w1, vf_w2, t_w1,
        ev1s, ev2s, ec1s, ec2s, cg1s, cg2s, cf1s, cf2s,
        vg1s, vg2s, vf1s, vf2s, t1s);

    // fused dual counting sort, rank-based (scatter has no atomics)
    hipMemsetAsync(cnt, 0, (size_t)nd * 4, stream);
    hist2<<<512, 256, 0, stream>>>(cons_idx, var_idx, NE, NC, cnt, ranks);
    scan_part<<<nb, 256, 0, stream>>>(cnt, nd, bsum);
    scan_bsum<<<1, 64, 0, stream>>>(bsum, nb);
    scan_final<<<nb, 256, 0, stream>>>(cnt, nd, bsum, basep);
    scatter2<<<1024, 256, 0, stream>>>(cons_idx, var_idx, e_val, ranks, NE, NC,
                                       basep, epk);

    node_mlp_in<19><<<(NV + 63) / 64, 256, 0, stream>>>(
        v, NV, ev1s, ev_b1, ev2s, ev_b2, v1bf);
    node_mlp_in<5><<<(NC + 63) / 64, 256, 0, stream>>>(
        c, NC, ec1s, ec_b1, ec2s, ec_b2, c1bf);

    // c-side conv + f-MLP
    hipMemsetAsync(agg_c, 0, (size_t)NC * 64 * 4, stream);
    edge_conv<<<1280, 256, 0, stream>>>(c1bf, v1bf, epk,
                                        cg1s, cg2s, cg_b1, cg_b2, agg_c, n_tiles);
    node_mlp_f<<<(NC + 63) / 64, 256, 0, stream>>>(
        c1bf, agg_c, NC, cf1s, cf_b1, cf2s, cf_b2, c2bf);

    // v-side conv + f-MLP + tail
    hipMemsetAsync(agg_v, 0, (size_t)NV * 64 * 4, stream);
    edge_conv<<<1280, 256, 0, stream>>>(v1bf, c2bf, epk + NE,
                                        vg1s, vg2s, vg_b1, vg_b2, agg_v, n_tiles);
    node_mlp_vf_tail<<<(NV + 63) / 64, 256, 0, stream>>>(
        v1bf, agg_v, NV, vf1s, vf_b1, vf2s, vf_b2,
        t1s, t_b1, t_w2, t_b2, (float*)d_out);
}

// Round 7
// 517.123 us; speedup vs baseline: 2.5229x; 1.0255x over previous
//
#include <hip/hip_runtime.h>
#include <hip/hip_bf16.h>

typedef short short8 __attribute__((ext_vector_type(8)));
typedef float f32x4 __attribute__((ext_vector_type(4)));
typedef unsigned short u16;
typedef unsigned int u32;

__device__ __forceinline__ u16 bf16rne(float f) {
    u32 u = __float_as_uint(f);
    u32 r = (u + 0x7fffu + ((u >> 16) & 1u)) >> 16;
    return (u16)r;
}
__device__ __forceinline__ float bf2f(u16 s) {
    return __uint_as_float(((u32)s) << 16);
}

// LDS-only barrier: wave-sync + LDS visibility WITHOUT draining vmcnt, so
// scatter atomics and prefetch loads stay in flight across barriers.
__device__ __forceinline__ void ldsbar() {
    asm volatile("s_waitcnt lgkmcnt(0)" ::: "memory");
    __builtin_amdgcn_s_barrier();
    asm volatile("" ::: "memory");
}

// ---------------------------------------------------------------------------
// Weight swizzle into MFMA B-fragment order, bf16 (unchanged).
// ---------------------------------------------------------------------------
__device__ __forceinline__ void swz(const float* __restrict__ src,
                                    u16* __restrict__ dst, int K, int KT,
                                    int tid0, int stride) {
    int total = 4 * KT * 512;
    for (int i = tid0; i < total; i += stride) {
        int j = i & 7, lane = (i >> 3) & 63, g = i >> 9;
        int kt = g % KT;
        int k = kt * 32 + (lane >> 4) * 8 + j;
        int n = (g / KT) * 16 + (lane & 15);
        dst[i] = (k < K) ? bf16rne(src[k * 64 + n]) : (u16)0;
    }
}

// ---------------------------------------------------------------------------
// Fused prep_weights (blocks [0,40)) + hist2 (blocks [40,552)).
// Independent stages -> one launch.
// ---------------------------------------------------------------------------
__global__ void prep_hist(
    const float* ev1, const float* ev2, const float* ec1, const float* ec2,
    const float* cg1, const float* cg2, const float* cf1, const float* cf2,
    const float* vg1, const float* vg2, const float* vf1, const float* vf2,
    const float* t1,
    u16* dev1, u16* dev2, u16* dec1, u16* dec2, u16* dcg1, u16* dcg2,
    u16* dcf1, u16* dcf2, u16* dvg1, u16* dvg2, u16* dvf1, u16* dvf2,
    u16* dt1,
    const int* __restrict__ ci, const int* __restrict__ vi, int ne, int nc,
    int* __restrict__ cnt, u32* __restrict__ ranks) {
    int b = blockIdx.x;
    if (b < 40) {
        int tid0 = b * blockDim.x + threadIdx.x;
        int st = 40 * blockDim.x;
        swz(ev1, dev1, 19, 1, tid0, st);
        swz(ev2, dev2, 64, 2, tid0, st);
        swz(ec1, dec1, 5, 1, tid0, st);
        swz(ec2, dec2, 64, 2, tid0, st);
        swz(cg1, dcg1, 129, 5, tid0, st);
        swz(cg2, dcg2, 64, 2, tid0, st);
        swz(cf1, dcf1, 128, 4, tid0, st);
        swz(cf2, dcf2, 64, 2, tid0, st);
        swz(vg1, dvg1, 129, 5, tid0, st);
        swz(vg2, dvg2, 64, 2, tid0, st);
        swz(vf1, dvf1, 128, 4, tid0, st);
        swz(vf2, dvf2, 64, 2, tid0, st);
        swz(t1, dt1, 64, 2, tid0, st);
    } else {
        int i = (b - 40) * blockDim.x + threadIdx.x;
        int st = 512 * blockDim.x;
        for (; i < ne; i += st) {
            int rc = atomicAdd(&cnt[ci[i]], 1);
            int rv = atomicAdd(&cnt[nc + vi[i]], 1);
            ranks[i] = ((u32)rc & 0xffffu) | ((u32)rv << 16);
        }
    }
}

// ---------------------------------------------------------------------------
// scan_part + last-block bsum scan (device-scope acquire/release).
// ---------------------------------------------------------------------------
#define SCAN_CHUNK 4096

__global__ void scan_part_bsum(const int* __restrict__ cnt, int nd,
                               int* __restrict__ bsum, int nb,
                               int* __restrict__ done) {
    __shared__ int sred[256];
    int b = blockIdx.x, t = threadIdx.x;
    int base = b * SCAN_CHUNK + t * 16;
    int s = 0;
#pragma unroll
    for (int j = 0; j < 16; j++) {
        int i = base + j;
        if (i < nd) s += cnt[i];
    }
    sred[t] = s;
    __syncthreads();
    for (int o = 128; o > 0; o >>= 1) {
        if (t < o) sred[t] += sred[t + o];
        __syncthreads();
    }
    if (t == 0) {
        __hip_atomic_store(&bsum[b], sred[0], __ATOMIC_RELEASE,
                           __HIP_MEMORY_SCOPE_AGENT);
        int prev = __hip_atomic_fetch_add(done, 1, __ATOMIC_ACQ_REL,
                                          __HIP_MEMORY_SCOPE_AGENT);
        if (prev == nb - 1) {
            int run = 0;
            for (int i = 0; i < nb; i++) {
                int vv = __hip_atomic_load(&bsum[i], __ATOMIC_ACQUIRE,
                                           __HIP_MEMORY_SCOPE_AGENT);
                __hip_atomic_store(&bsum[i], run, __ATOMIC_RELAXED,
                                   __HIP_MEMORY_SCOPE_AGENT);
                run += vv;
            }
        }
    }
}

__global__ void scan_final(const int* __restrict__ cnt, int nd,
                           const int* __restrict__ bsum,
                           int* __restrict__ basep) {
    __shared__ int sa[256];
    int b = blockIdx.x, t = threadIdx.x;
    int base = b * SCAN_CHUNK + t * 16;
    int loc[16];
    int s = 0;
#pragma unroll
    for (int j = 0; j < 16; j++) {
        int i = base + j;
        int v = (i < nd) ? cnt[i] : 0;
        loc[j] = s;
        s += v;
    }
    sa[t] = s;
    __syncthreads();
    int inc = s;
    for (int o = 1; o < 256; o <<= 1) {
        int v = (t >= o) ? sa[t - o] : 0;
        __syncthreads();
        sa[t] += v;
        __syncthreads();
    }
    int off = bsum[b] + sa[t] - inc;
#pragma unroll
    for (int j = 0; j < 16; j++) {
        int i = base + j;
        if (i < nd) basep[i] = off + loc[j];
    }
}

// ---------------------------------------------------------------------------
// Generic MFMA layer (unchanged).
// ---------------------------------------------------------------------------
template <int KT, int SA>
__device__ __forceinline__ void mfma_layer(const u16* __restrict__ Asrc,
                                           const short8* wf, float bv,
                                           u16* __restrict__ Hdst,
                                           int l15, int lq, int w) {
#pragma unroll
    for (int mt = 0; mt < 4; mt++) {
        f32x4 acc = {0.f, 0.f, 0.f, 0.f};
#pragma unroll
        for (int kt = 0; kt < KT; kt++) {
            short8 a = *(const short8*)(Asrc + (mt * 16 + l15) * SA + kt * 32 + lq * 8);
            acc = __builtin_amdgcn_mfma_f32_16x16x32_bf16(a, wf[kt], acc, 0, 0, 0);
        }
#pragma unroll
        for (int r = 0; r < 4; r++)
            Hdst[(mt * 16 + lq * 4 + r) * 72 + w * 16 + l15] =
                bf16rne(fmaxf(acc[r] + bv, 0.f));
    }
}

// ---------------------------------------------------------------------------
// Input node MLP body (device fn on a shared smem arena).
// ---------------------------------------------------------------------------
template <int KIN>
__device__ __forceinline__ void mlp_in_body(
    const float* __restrict__ x, int n_nodes,
    const u16* __restrict__ w1s, const float* __restrict__ b1,
    const u16* __restrict__ w2s, const float* __restrict__ b2,
    u16* __restrict__ outbf, int blkid, u16* __restrict__ smem) {
    u16* A = smem;                 // 64*40
    u16* H1 = smem + 64 * 40;      // 64*72
    u16* H2 = H1 + 64 * 72;        // 64*72
    int tid = threadIdx.x, l = tid & 63, w = tid >> 6;
    int l15 = l & 15, lq = l >> 4;
    int blk0 = blkid * 64;
    const int PW = 40 - KIN;
    for (int i = tid; i < 64 * PW; i += 256) {
        int r = i / PW, cc = KIN + (i - r * PW);
        A[r * 40 + cc] = 0;
    }
    for (int i = tid; i < 64 * KIN; i += 256) {
        int r = i / KIN, k = i - r * KIN;
        int gn = blk0 + r; if (gn >= n_nodes) gn = n_nodes - 1;
        A[r * 40 + k] = bf16rne(x[(size_t)gn * KIN + k]);
    }
    short8 w1f[1], w2f[2];
    w1f[0] = *(const short8*)(w1s + ((w * 1 + 0) * 64 + l) * 8);
#pragma unroll
    for (int kt = 0; kt < 2; kt++)
        w2f[kt] = *(const short8*)(w2s + ((w * 2 + kt) * 64 + l) * 8);
    float b1v = b1[w * 16 + l15], b2v = b2[w * 16 + l15];
    ldsbar();
    mfma_layer<1, 40>(A, w1f, b1v, H1, l15, lq, w);
    ldsbar();
    mfma_layer<2, 72>(H1, w2f, b2v, H2, l15, lq, w);
    ldsbar();
    for (int i = tid; i < 512; i += 256) {
        int r = i >> 3, c = i & 7;
        if (blk0 + r < n_nodes)
            *(uint4*)(outbf + (size_t)(blk0 + r) * 64 + c * 8) =
                *(const uint4*)(H2 + r * 72 + c * 8);
    }
}

// ---------------------------------------------------------------------------
// Mega kernel: scatter (blocks [0,512)) || mlp_in v || mlp_in c ||
// zero agg_c+agg_v (last 256 blocks). All independent once scan_final done.
// Scatter blocks first so their memory traffic overlaps MLP MFMA compute.
// ---------------------------------------------------------------------------
#define MEGA_SC 512
#define MEGA_ZB 256

__global__ __launch_bounds__(256, 6) void mega(
    const int* __restrict__ ci, const int* __restrict__ vi,
    const float* __restrict__ ev, const u32* __restrict__ ranks,
    int ne, int nc, int nv, const int* __restrict__ basep,
    int4* __restrict__ epk,
    const float* __restrict__ vx, const u16* __restrict__ ev1s,
    const float* __restrict__ ev_b1, const u16* __restrict__ ev2s,
    const float* __restrict__ ev_b2, u16* __restrict__ v1bf,
    const float* __restrict__ cx, const u16* __restrict__ ec1s,
    const float* __restrict__ ec_b1, const u16* __restrict__ ec2s,
    const float* __restrict__ ec_b2, u16* __restrict__ c1bf,
    float* __restrict__ agg_c, float* __restrict__ agg_v) {
    __shared__ __align__(16) u16 smem[64 * 40 + 2 * 64 * 72];
    int b = blockIdx.x;
    int nb_v = (nv + 63) >> 6;
    int nb_c = (nc + 63) >> 6;
    if (b < MEGA_SC) {
        int i = b * 256 + threadIdx.x;
        int st = MEGA_SC * 256;
        for (; i < ne; i += st) {
            int cd = ci[i], vd = vi[i];
            u32 rk = ranks[i];
            int eb = __float_as_int(ev[i]);
            int pc = basep[cd] + (int)(rk & 0xffffu);
            int pv = basep[nc + vd] + (int)(rk >> 16);
            epk[pc] = make_int4(cd, vd, eb, 0);
            epk[pv] = make_int4(vd, cd, eb, 0);
        }
    } else if (b < MEGA_SC + nb_v) {
        mlp_in_body<19>(vx, nv, ev1s, ev_b1, ev2s, ev_b2, v1bf, b - MEGA_SC, smem);
    } else if (b < MEGA_SC + nb_v + nb_c) {
        mlp_in_body<5>(cx, nc, ec1s, ec_b1, ec2s, ec_b2, c1bf,
                       b - MEGA_SC - nb_v, smem);
    } else {
        int zb = b - MEGA_SC - nb_v - nb_c;          // 0..MEGA_ZB-1
        size_t nct = (size_t)nc * 64;
        size_t total = nct + (size_t)nv * 64;
        float4 z = {0.f, 0.f, 0.f, 0.f};
        size_t i = ((size_t)zb * 256 + threadIdx.x) * 4;
        size_t stp = (size_t)MEGA_ZB * 256 * 4;
        for (; i < total; i += stp) {
            if (i < nct) *(float4*)(agg_c + i) = z;
            else         *(float4*)(agg_v + (i - nct)) = z;
        }
    }
}

// ---------------------------------------------------------------------------
// f-MLP staging (unchanged).
// ---------------------------------------------------------------------------
__device__ __forceinline__ void stage_concat_res(
    const u16* __restrict__ ubf, const float* __restrict__ agg,
    int blk0, int n_nodes, u16* __restrict__ A, int tid) {
    for (int i = tid; i < 64 * 24; i += 256) {
        int nd = i / 24, c = i - nd * 24;
        int gn = blk0 + nd; if (gn >= n_nodes) gn = n_nodes - 1;
        if (c < 8) {
            *(uint4*)(A + nd * 200 + c * 8) =
                *(const uint4*)(ubf + (size_t)gn * 64 + c * 8);
        } else {
            int q = c - 8;
            float4 av = *(const float4*)(agg + (size_t)gn * 64 + q * 4);
            u16 h0 = bf16rne(av.x), h1 = bf16rne(av.y);
            u16 h2 = bf16rne(av.z), h3 = bf16rne(av.w);
            uint2 hi;
            hi.x = (u32)h0 | ((u32)h1 << 16);
            hi.y = (u32)h2 | ((u32)h3 << 16);
            *(uint2*)(A + nd * 200 + 64 + q * 4) = hi;
            uint2 rs;
            rs.x = (u32)bf16rne(av.x - bf2f(h0)) | ((u32)bf16rne(av.y - bf2f(h1)) << 16);
            rs.y = (u32)bf16rne(av.z - bf2f(h2)) | ((u32)bf16rne(av.w - bf2f(h3)) << 16);
            *(uint2*)(A + nd * 200 + 128 + q * 4) = rs;
        }
    }
}

// ---------------------------------------------------------------------------
// c-side f-MLP (unchanged).
// ---------------------------------------------------------------------------
__global__ __launch_bounds__(256, 4) void node_mlp_f(
    const u16* __restrict__ ubf, const float* __restrict__ agg, int n_nodes,
    const u16* __restrict__ w1s, const float* __restrict__ b1,
    const u16* __restrict__ w2s, const float* __restrict__ b2,
    u16* __restrict__ outbf) {
    __shared__ __align__(16) u16 A[64 * 200];
    __shared__ __align__(16) u16 H1[64 * 72];
    int tid = threadIdx.x, l = tid & 63, w = tid >> 6;
    int l15 = l & 15, lq = l >> 4;
    int blk0 = blockIdx.x * 64;
    stage_concat_res(ubf, agg, blk0, n_nodes, A, tid);
    short8 w1f[6], w2f[2];
#pragma unroll
    for (int kt = 0; kt < 4; kt++)
        w1f[kt] = *(const short8*)(w1s + ((w * 4 + kt) * 64 + l) * 8);
    w1f[4] = w1f[2];
    w1f[5] = w1f[3];
#pragma unroll
    for (int kt = 0; kt < 2; kt++)
        w2f[kt] = *(const short8*)(w2s + ((w * 2 + kt) * 64 + l) * 8);
    float b1v = b1[w * 16 + l15], b2v = b2[w * 16 + l15];
    ldsbar();
    mfma_layer<6, 200>(A, w1f, b1v, H1, l15, lq, w);
    ldsbar();
    mfma_layer<2, 72>(H1, w2f, b2v, A, l15, lq, w);
    ldsbar();
    for (int i = tid; i < 512; i += 256) {
        int r = i >> 3, c = i & 7;
        if (blk0 + r < n_nodes)
            *(uint4*)(outbf + (size_t)(blk0 + r) * 64 + c * 8) =
                *(const uint4*)(A + r * 72 + c * 8);
    }
}

// ---------------------------------------------------------------------------
// v-side f-MLP + tail (unchanged).
// ---------------------------------------------------------------------------
__global__ __launch_bounds__(256, 3) void node_mlp_vf_tail(
    const u16* __restrict__ vbf, const float* __restrict__ agg, int n_nodes,
    const u16* __restrict__ w1s, const float* __restrict__ b1,
    const u16* __restrict__ w2s, const float* __restrict__ b2,
    const u16* __restrict__ t1s, const float* __restrict__ tb1,
    const float* __restrict__ tw2, const float* __restrict__ tb2,
    float* __restrict__ out) {
    __shared__ __align__(16) char smem[64 * 200 * 2 + 2 * 64 * 72 * 2];
    u16* A = (u16*)smem;
    float* XF = (float*)smem;
    u16* H1 = (u16*)(smem + 25600);
    u16* H2 = (u16*)(smem + 25600 + 9216);
    int tid = threadIdx.x, l = tid & 63, w = tid >> 6;
    int l15 = l & 15, lq = l >> 4;
    int blk0 = blockIdx.x * 64;
    stage_concat_res(vbf, agg, blk0, n_nodes, A, tid);
    short8 w1f[6], w2f[2], t1f[2];
#pragma unroll
    for (int kt = 0; kt < 4; kt++)
        w1f[kt] = *(const short8*)(w1s + ((w * 4 + kt) * 64 + l) * 8);
    w1f[4] = w1f[2];
    w1f[5] = w1f[3];
#pragma unroll
    for (int kt = 0; kt < 2; kt++) {
        w2f[kt] = *(const short8*)(w2s + ((w * 2 + kt) * 64 + l) * 8);
        t1f[kt] = *(const short8*)(t1s + ((w * 2 + kt) * 64 + l) * 8);
    }
    float b1v = b1[w * 16 + l15], b2v = b2[w * 16 + l15];
    float tb1v = tb1[w * 16 + l15];
    ldsbar();
    mfma_layer<6, 200>(A, w1f, b1v, H1, l15, lq, w);
    ldsbar();
    mfma_layer<2, 72>(H1, w2f, b2v, H2, l15, lq, w);
    ldsbar();
#pragma unroll
    for (int mt = 0; mt < 4; mt++) {
        f32x4 acc = {0.f, 0.f, 0.f, 0.f};
#pragma unroll
        for (int kt = 0; kt < 2; kt++) {
            short8 a = *(const short8*)(H2 + (mt * 16 + l15) * 72 + kt * 32 + lq * 8);
            acc = __builtin_amdgcn_mfma_f32_16x16x32_bf16(a, t1f[kt], acc, 0, 0, 0);
        }
#pragma unroll
        for (int r = 0; r < 4; r++)
            XF[(mt * 16 + lq * 4 + r) * 65 + w * 16 + l15] =
                fmaxf(acc[r] + tb1v, 0.f);
    }
    ldsbar();
    float s0 = tb2[2 * w], s1 = tb2[2 * w + 1];
    for (int k = 0; k < 64; k++) {
        float xk = XF[l * 65 + k];
        float2 wp = *(const float2*)(tw2 + k * 8 + 2 * w);
        s0 = fmaf(xk, wp.x, s0);
        s1 = fmaf(xk, wp.y, s1);
    }
    if (blk0 + l < n_nodes) {
        float2 r;
        r.x = 1.f / (1.f + __expf(-s0));
        r.y = 1.f / (1.f + __expf(-s1));
        *(float2*)(out + (size_t)(blk0 + l) * 8 + 2 * w) = r;
    }
}

// ---------------------------------------------------------------------------
// Edge conv: unchanged from R6 (proven 114 us/dispatch).
// ---------------------------------------------------------------------------
#define AROW 168
#define HROW 72

__global__ __launch_bounds__(256, 5) void edge_conv(
    const u16* __restrict__ u_feat, const u16* __restrict__ v_feat,
    const int4* __restrict__ epk,   // sorted packed edges {dst, src, ev, 0}
    const u16* __restrict__ w1s, const u16* __restrict__ w2s,
    const float* __restrict__ b1, const float* __restrict__ b2,
    float* __restrict__ agg, int n_tiles) {
    __shared__ __align__(16) u16 A[64 * AROW];   // staging; later G (f32) overlay
    __shared__ __align__(16) u16 Hs[64 * HROW];
    __shared__ int Didx[64];

    int tid = threadIdx.x;
    int lane = tid & 63;
    int w = tid >> 6;
    int l15 = lane & 15, lq = lane >> 4;
    int cch = tid & 15, e0 = tid >> 4;

    for (int i = tid; i < 64 * (AROW - 129); i += 256) {
        int r = i / (AROW - 129);
        int cc = 129 + (i - r * (AROW - 129));
        A[r * AROW + cc] = 0;
    }

    short8 w1f[5], w2f[2];
#pragma unroll
    for (int kt = 0; kt < 5; kt++)
        w1f[kt] = *(const short8*)(w1s + ((w * 5 + kt) * 64 + lane) * 8);
#pragma unroll
    for (int kt = 0; kt < 2; kt++)
        w2f[kt] = *(const short8*)(w2s + ((w * 2 + kt) * 64 + lane) * 8);
    float b1v = b1[w * 16 + l15];
    float b2v = b2[w * 16 + l15];

    const bool fsel = (cch < 8);
    const u16* fbase = fsel ? u_feat : v_feat;
    const int gcol = fsel ? cch * 8 : 64 + (cch - 8) * 8;
    const int coff = (cch & 7) * 8;
    const int* epki = (const int*)epk;

    const int G = gridDim.x;
    int tile = (int)blockIdx.x;

    uint4 st[4];
    u32 evb[4];
    int4 pe[4];
    int didx_c = 0, didx_n = 0;

    if (tile < n_tiles) {
#pragma unroll
        for (int t = 0; t < 4; t++) {
            int ge = tile * 64 + e0 + t * 16;
            int4 e = epk[ge];
            int ix = fsel ? e.x : e.y;
            st[t] = *(const uint4*)(fbase + (size_t)ix * 64 + coff);
            evb[t] = (u32)e.z;
        }
        if (tid < 64) didx_c = epki[(tile * 64 + tid) * 4];
        int ntp = tile + G;
        if (ntp < n_tiles) {
#pragma unroll
            for (int t = 0; t < 4; t++) pe[t] = epk[ntp * 64 + e0 + t * 16];
        }
    }

    for (; tile < n_tiles; tile += G) {
        ldsbar();  // B0: prev seg-reduce reads of G done before commit writes
#pragma unroll
        for (int t = 0; t < 4; t++) {
            int e = e0 + t * 16;
            *(uint4*)(&A[e * AROW + gcol]) = st[t];
            if (cch == 0) A[e * AROW + 128] = bf16rne(__uint_as_float(evb[t]));
        }
        int nt = tile + G;
        if (nt < n_tiles) {
#pragma unroll
            for (int t = 0; t < 4; t++) {
                int ix = fsel ? pe[t].x : pe[t].y;
                st[t] = *(const uint4*)(fbase + (size_t)ix * 64 + coff);
                evb[t] = (u32)pe[t].z;
            }
            if (tid < 64) didx_n = epki[(nt * 64 + tid) * 4];
            int nt2 = nt + G;
            if (nt2 < n_tiles) {
#pragma unroll
                for (int t = 0; t < 4; t++)
                    pe[t] = epk[nt2 * 64 + e0 + t * 16];
            }
        }
        ldsbar();  // B1: A staged (LDS only; atomics/prefetch stay in flight)

#pragma unroll
        for (int mt = 0; mt < 4; mt++) {
            short8 a1[5];
#pragma unroll
            for (int kt = 0; kt < 5; kt++)
                a1[kt] = *(const short8*)(&A[(mt * 16 + l15) * AROW + kt * 32 + lq * 8]);
            f32x4 acc = {0.f, 0.f, 0.f, 0.f};
#pragma unroll
            for (int kt = 0; kt < 5; kt++)
                acc = __builtin_amdgcn_mfma_f32_16x16x32_bf16(a1[kt], w1f[kt], acc, 0, 0, 0);
#pragma unroll
            for (int r = 0; r < 4; r++) {
                float hv = fmaxf(acc[r] + b1v, 0.f);
                Hs[(mt * 16 + lq * 4 + r) * HROW + w * 16 + l15] = bf16rne(hv);
            }
        }
        ldsbar();  // B2: Hs ready; A reads done -> A region free for G

        float* Gf = (float*)A;  // row stride 84 floats; cols 0..63 used
#pragma unroll
        for (int mt = 0; mt < 4; mt++) {
            short8 a2[2];
#pragma unroll
            for (int kt = 0; kt < 2; kt++)
                a2[kt] = *(const short8*)(&Hs[(mt * 16 + l15) * HROW + kt * 32 + lq * 8]);
            f32x4 acc = {0.f, 0.f, 0.f, 0.f};
#pragma unroll
            for (int kt = 0; kt < 2; kt++)
                acc = __builtin_amdgcn_mfma_f32_16x16x32_bf16(a2[kt], w2f[kt], acc, 0, 0, 0);
#pragma unroll
            for (int r = 0; r < 4; r++)
                Gf[(mt * 16 + lq * 4 + r) * 84 + w * 16 + l15] =
                    fmaxf(acc[r] + b2v, 0.f);
        }
        if (tid < 64) Didx[tid] = didx_c;
        ldsbar();  // B3: G + Didx ready

        {
            int col = tid & 63, rg = tid >> 6;
            int r0 = rg * 16;
            int dcur = Didx[r0];
            float s = Gf[r0 * 84 + col];
#pragma unroll
            for (int r = 1; r < 16; r++) {
                int d = Didx[r0 + r];
                float g = Gf[(r0 + r) * 84 + col];
                if (d != dcur) {
                    __hip_atomic_fetch_add(&agg[(size_t)dcur * 64 + col], s,
                                           __ATOMIC_RELAXED, __HIP_MEMORY_SCOPE_AGENT);
                    dcur = d;
                    s = g;
                } else {
                    s += g;
                }
            }
            __hip_atomic_fetch_add(&agg[(size_t)dcur * 64 + col], s,
                                   __ATOMIC_RELAXED, __HIP_MEMORY_SCOPE_AGENT);
        }
        didx_c = didx_n;
    }
}

extern "C" void kernel_launch(void* const* d_in, const int* in_sizes, int n_in,
                              void* d_out, int out_size, void* d_ws, size_t ws_size,
                              hipStream_t stream) {
    const float* v        = (const float*)d_in[0];
    const float* c        = (const float*)d_in[1];
    const int*   cons_idx = (const int*)d_in[2];
    const int*   var_idx  = (const int*)d_in[3];
    const float* e_val    = (const float*)d_in[4];
    const float* ev_w1 = (const float*)d_in[5],  *ev_b1 = (const float*)d_in[6];
    const float* ev_w2 = (const float*)d_in[7],  *ev_b2 = (const float*)d_in[8];
    const float* ec_w1 = (const float*)d_in[9],  *ec_b1 = (const float*)d_in[10];
    const float* ec_w2 = (const float*)d_in[11], *ec_b2 = (const float*)d_in[12];
    const float* cg_w1 = (const float*)d_in[13], *cg_b1 = (const float*)d_in[14];
    const float* cg_w2 = (const float*)d_in[15], *cg_b2 = (const float*)d_in[16];
    const float* cf_w1 = (const float*)d_in[17], *cf_b1 = (const float*)d_in[18];
    const float* cf_w2 = (const float*)d_in[19], *cf_b2 = (const float*)d_in[20];
    const float* vg_w1 = (const float*)d_in[21], *vg_b1 = (const float*)d_in[22];
    const float* vg_w2 = (const float*)d_in[23], *vg_b2 = (const float*)d_in[24];
    const float* vf_w1 = (const float*)d_in[25], *vf_b1 = (const float*)d_in[26];
    const float* vf_w2 = (const float*)d_in[27], *vf_b2 = (const float*)d_in[28];
    const float* t_w1  = (const float*)d_in[29], *t_b1  = (const float*)d_in[30];
    const float* t_w2  = (const float*)d_in[31], *t_b2  = (const float*)d_in[32];

    const int NV = in_sizes[0] / 19;
    const int NC = in_sizes[1] / 5;
    const int NE = in_sizes[4];

    char* ws = (char*)d_ws;
    size_t off = 0;
    u16* v1bf = (u16*)(ws + off); off += (size_t)NV * 64 * 2;
    u16* c1bf = (u16*)(ws + off); off += (size_t)NC * 64 * 2;
    u16* c2bf = (u16*)(ws + off); off += (size_t)NC * 64 * 2;
    float* agg_c = (float*)(ws + off); off += (size_t)NC * 64 * 4;
    float* agg_v = (float*)(ws + off); off += (size_t)NV * 64 * 4;
    u16* ev1s = (u16*)(ws + off); off += 2048 * 2;
    u16* ev2s = (u16*)(ws + off); off += 4096 * 2;
    u16* ec1s = (u16*)(ws + off); off += 2048 * 2;
    u16* ec2s = (u16*)(ws + off); off += 4096 * 2;
    u16* cg1s = (u16*)(ws + off); off += 10240 * 2;
    u16* cg2s = (u16*)(ws + off); off += 4096 * 2;
    u16* cf1s = (u16*)(ws + off); off += 8192 * 2;
    u16* cf2s = (u16*)(ws + off); off += 4096 * 2;
    u16* vg1s = (u16*)(ws + off); off += 10240 * 2;
    u16* vg2s = (u16*)(ws + off); off += 4096 * 2;
    u16* vf1s = (u16*)(ws + off); off += 8192 * 2;
    u16* vf2s = (u16*)(ws + off); off += 4096 * 2;
    u16* t1s  = (u16*)(ws + off); off += 4096 * 2;
    off = (off + 255) & ~(size_t)255;
    int* cnt    = (int*)(ws + off); off += (size_t)(NC + NV) * 4;
    int* done   = (int*)(ws + off); off += 4;          // contiguous after cnt
    off = (off + 255) & ~(size_t)255;
    int* basep  = (int*)(ws + off); off += (size_t)(NC + NV) * 4;
    int* bsum   = (int*)(ws + off); off += 64 * 4;
    off = (off + 255) & ~(size_t)255;
    u32* ranks  = (u32*)(ws + off); off += (size_t)NE * 4;
    off = (off + 255) & ~(size_t)255;
    int4* epk   = (int4*)(ws + off); off += (size_t)NE * 2 * 16;

    const int n_tiles = NE / 64;
    const int nd = NC + NV;
    const int nb = (nd + SCAN_CHUNK - 1) / SCAN_CHUNK;
    const int nb_v = (NV + 63) / 64;
    const int nb_c = (NC + 63) / 64;

    // zero cnt + done in one memset (contiguous)
    hipMemsetAsync(cnt, 0, (size_t)nd * 4 + 4, stream);

    // 1) prep_weights || hist2
    prep_hist<<<552, 256, 0, stream>>>(
        ev_w1, ev_w2, ec_w1, ec_w2, cg_w1, cg_w2, cf_w1, cf_w2,
        vg_w1, vg_w2, vf_w1, vf_w2, t_w1,
        ev1s, ev2s, ec1s, ec2s, cg1s, cg2s, cf1s, cf2s,
        vg1s, vg2s, vf1s, vf2s, t1s,
        cons_idx, var_idx, NE, NC, cnt, (u32*)ranks);

    // 2) scan (block partials + fused last-block bsum scan), then bases
    scan_part_bsum<<<nb, 256, 0, stream>>>(cnt, nd, bsum, nb, done);
    scan_final<<<nb, 256, 0, stream>>>(cnt, nd, bsum, basep);

    // 3) scatter || mlp_in v || mlp_in c || zero aggs
    mega<<<MEGA_SC + nb_v + nb_c + MEGA_ZB, 256, 0, stream>>>(
        cons_idx, var_idx, e_val, ranks, NE, NC, NV, basep, epk,
        v, ev1s, ev_b1, ev2s, ev_b2, v1bf,
        c, ec1s, ec_b1, ec2s, ec_b2, c1bf,
        agg_c, agg_v);

    // 4) c-side conv + f-MLP
    edge_conv<<<1280, 256, 0, stream>>>(c1bf, v1bf, epk,
                                        cg1s, cg2s, cg_b1, cg_b2, agg_c, n_tiles);
    node_mlp_f<<<nb_c, 256, 0, stream>>>(
        c1bf, agg_c, NC, cf1s, cf_b1, cf2s, cf_b2, c2bf);

    // 5) v-side conv + f-MLP + tail
    edge_conv<<<1280, 256, 0, stream>>>(v1bf, c2bf, epk + NE,
                                        vg1s, vg2s, vg_b1, vg_b2, agg_v, n_tiles);
    node_mlp_vf_tail<<<nb_v, 256, 0, stream>>>(
        v1bf, agg_v, NV, vf1s, vf_b1, vf2s, vf_b2,
        t1s, t_b1, t_w2, t_b2, (float*)d_out);
}